// Round 12
// baseline (277.032 us; speedup 1.0000x reference)
//
#include <hip/hip_runtime.h>
#include <hip/hip_bf16.h>
#include <math.h>

#define LN_EPS 1e-5f

typedef __attribute__((ext_vector_type(8))) short short8v;
typedef __attribute__((ext_vector_type(4))) float f32x4;

static __device__ __forceinline__ unsigned short f2bf(float x) {
    unsigned u = __float_as_uint(x);
    u += 0x7fffu + ((u >> 16) & 1u);
    return (unsigned short)(u >> 16);
}
static __device__ __forceinline__ float bf2f(unsigned short h) {
    return __uint_as_float(((unsigned)h) << 16);
}

#define MFMA3(ACC, AH, AL, BH, BL)                                          \
    ACC = __builtin_amdgcn_mfma_f32_16x16x32_bf16(AH, BH, ACC, 0, 0, 0);    \
    ACC = __builtin_amdgcn_mfma_f32_16x16x32_bf16(AL, BH, ACC, 0, 0, 0);    \
    ACC = __builtin_amdgcn_mfma_f32_16x16x32_bf16(AH, BL, ACC, 0, 0, 0);

// ---------------------------------------------------------------------------
// K1: per-patch conv1+pool (f32 VALU) -> conv2 (MFMA im2col) + shfl-pool
//     -> expansion. 512 threads (8 waves), 2 blocks/CU.
// r12: W LDS lg-stride padded 256->264 slots (ks stride 1024->1056) so the
// four lg groups hit distinct bank-quads (was 4-way conflict on every W read).
// ---------------------------------------------------------------------------
__global__ __launch_bounds__(512, 4) void k_conv(
    const float* __restrict__ t,
    const float* __restrict__ c1w, const float* __restrict__ c1b,
    const float* __restrict__ c2w, const float* __restrict__ c2b,
    const float* __restrict__ ew,  const float* __restrict__ eb,
    float* __restrict__ u)
{
    __shared__ __align__(16) unsigned short s_W2[2][9504];   // 38016 B
    __shared__ __align__(16) unsigned short s_p1h[4 * 225 * 8];  // 14400 B
    __shared__ __align__(16) unsigned short s_p1l[4 * 225 * 8];  // 14400 B
    __shared__ __align__(16) float s_s2[32 * 36];            // 4608 B
    __shared__ float s_c2b[32];

    float* s_x  = (float*)s_W2;
    float* s_ew = (float*)s_p1h;
    unsigned short* s_wh = s_W2[0];
    unsigned short* s_wl = s_W2[1];

    const int p   = blockIdx.x;
    const int tid = threadIdx.x;

    const int b = p >> 4, tile = p & 15, tr = tile >> 2, tc = tile & 3;
    const float* tp = t + (size_t)b * 128 * 128 + (size_t)tr * 32 * 128 + tc * 32;
    for (int i = tid; i < 1024; i += 512) {
        const int r = i >> 5, c = i & 31;
        s_x[r * 33 + c] = tp[r * 128 + c] * (1.0f / 255.0f);
    }
    if (tid < 32) s_c2b[tid] = c2b[tid];
    __syncthreads();

    if ((tid & 255) < 225) {
        const int pos  = tid & 255;
        const int half = tid >> 8;
        const int pi = pos / 15, pj = pos % 15;
        float xw[16];
        #pragma unroll
        for (int r = 0; r < 4; ++r)
            #pragma unroll
            for (int c = 0; c < 4; ++c)
                xw[r * 4 + c] = s_x[(2 * pi + r) * 33 + (2 * pj + c)];
        #pragma unroll
        for (int og2 = 0; og2 < 2; ++og2) {
            const int og = half * 2 + og2;
            short8v hb, lb;
            #pragma unroll
            for (int o = 0; o < 8; ++o) {
                const int oc = og * 8 + o;
                float w[9];
                #pragma unroll
                for (int j = 0; j < 9; ++j) w[j] = c1w[oc * 9 + j];
                float mx = -3.0e38f;
                #pragma unroll
                for (int a = 0; a < 2; ++a)
                    #pragma unroll
                    for (int bb = 0; bb < 2; ++bb) {
                        float s = xw[(a + 0) * 4 + bb + 0] * w[0]
                                + xw[(a + 0) * 4 + bb + 1] * w[1]
                                + xw[(a + 0) * 4 + bb + 2] * w[2]
                                + xw[(a + 1) * 4 + bb + 0] * w[3]
                                + xw[(a + 1) * 4 + bb + 1] * w[4]
                                + xw[(a + 1) * 4 + bb + 2] * w[5]
                                + xw[(a + 2) * 4 + bb + 0] * w[6]
                                + xw[(a + 2) * 4 + bb + 1] * w[7]
                                + xw[(a + 2) * 4 + bb + 2] * w[8];
                        mx = fmaxf(mx, s);
                    }
                const float val = mx + c1b[oc];
                const unsigned short h = f2bf(val);
                hb[o] = (short)h;
                lb[o] = (short)f2bf(val - bf2f(h));
            }
            *(short8v*)&s_p1h[og * 1800 + pos * 8] = hb;
            *(short8v*)&s_p1l[og * 1800 + pos * 8] = lb;
        }
    }
    __syncthreads();

    // ---- stage c2w -> s_wh/s_wl [ks][kg(264)][oc][8] (overwrites s_x) ----
    {
        const int oc  = tid >> 4;
        const int sub = tid & 15;
        const int kg  = sub >> 2;
        const int off = (sub * 2) & 7;
        const float* wp = c2w + oc * 288 + sub * 18;
        float wf[18];
        #pragma unroll
        for (int j = 0; j < 9; ++j)
            *(float2*)&wf[j * 2] = *(const float2*)&wp[j * 2];
        #pragma unroll
        for (int ks = 0; ks < 9; ++ks) {
            const float v0 = wf[ks];
            const float v1 = wf[9 + ks];
            const unsigned short h0 = f2bf(v0), h1 = f2bf(v1);
            const unsigned short l0 = f2bf(v0 - bf2f(h0));
            const unsigned short l1 = f2bf(v1 - bf2f(h1));
            const int idx = ks * 1056 + kg * 264 + oc * 8 + off;
            *(unsigned*)&s_wh[idx] = (unsigned)h0 | ((unsigned)h1 << 16);
            *(unsigned*)&s_wl[idx] = (unsigned)l0 | ((unsigned)l1 << 16);
        }
    }
    __syncthreads();

    {
        const int lane = tid & 63;
        const int w8   = tid >> 6;
        const int jcol = lane & 15;
        const int lg   = lane >> 4;

        {
            const int nt = w8;
            const int n = nt * 16 + jcol;
            const int pq = n >> 2, w4 = n & 3;
            const int pi = pq / 6, pj = pq - pi * 6;
            const int rbase = 2 * pi + (w4 >> 1);
            const int cbase = 2 * pj + (w4 & 1);

            f32x4 acc0 = {0,0,0,0}, acc1 = {0,0,0,0};
            #pragma unroll
            for (int ks = 0; ks < 9; ++ks) {
                const int dr = ks / 3, dc = ks - dr * 3;
                const int ab = ks * 1056 + lg * 264 + jcol * 8;
                const short8v ah0 = *(const short8v*)&s_wh[ab];
                const short8v ah1 = *(const short8v*)&s_wh[ab + 128];
                const short8v al0 = *(const short8v*)&s_wl[ab];
                const short8v al1 = *(const short8v*)&s_wl[ab + 128];
                const int wpos = (rbase + dr) * 15 + (cbase + dc);
                const int boff = lg * 1800 + wpos * 8;
                const short8v bh = *(const short8v*)&s_p1h[boff];
                const short8v bl = *(const short8v*)&s_p1l[boff];
                acc0 = __builtin_amdgcn_mfma_f32_16x16x32_bf16(ah0, bh, acc0, 0, 0, 0);
                acc0 = __builtin_amdgcn_mfma_f32_16x16x32_bf16(al0, bh, acc0, 0, 0, 0);
                acc0 = __builtin_amdgcn_mfma_f32_16x16x32_bf16(ah0, bl, acc0, 0, 0, 0);
                acc1 = __builtin_amdgcn_mfma_f32_16x16x32_bf16(ah1, bh, acc1, 0, 0, 0);
                acc1 = __builtin_amdgcn_mfma_f32_16x16x32_bf16(al1, bh, acc1, 0, 0, 0);
                acc1 = __builtin_amdgcn_mfma_f32_16x16x32_bf16(ah1, bl, acc1, 0, 0, 0);
            }
            #pragma unroll
            for (int mt = 0; mt < 2; ++mt)
                #pragma unroll
                for (int r = 0; r < 4; ++r) {
                    float v = (mt == 0) ? acc0[r] : acc1[r];
                    v = fmaxf(v, __shfl_xor(v, 1));
                    v = fmaxf(v, __shfl_xor(v, 2));
                    if ((lane & 3) == 0) {
                        const int oc = mt * 16 + (lane >> 4) * 4 + r;
                        const int pq2 = nt * 4 + (jcol >> 2);
                        s_s2[oc * 36 + pq2] = v + s_c2b[oc];
                    }
                }
        }

        if (w8 < 2) {
            const int nt = 8;
            const int mt = w8;
            const int n = nt * 16 + jcol;
            const int pq = n >> 2, w4 = n & 3;
            const int pi = pq / 6, pj = pq - pi * 6;
            const int rbase = 2 * pi + (w4 >> 1);
            const int cbase = 2 * pj + (w4 & 1);

            f32x4 accX = {0,0,0,0};
            #pragma unroll
            for (int ks = 0; ks < 9; ++ks) {
                const int dr = ks / 3, dc = ks - dr * 3;
                const int ab = ks * 1056 + lg * 264 + jcol * 8 + mt * 128;
                const short8v ah = *(const short8v*)&s_wh[ab];
                const short8v al = *(const short8v*)&s_wl[ab];
                const int wpos = (rbase + dr) * 15 + (cbase + dc);
                const int boff = lg * 1800 + wpos * 8;
                const short8v bh = *(const short8v*)&s_p1h[boff];
                const short8v bl = *(const short8v*)&s_p1l[boff];
                accX = __builtin_amdgcn_mfma_f32_16x16x32_bf16(ah, bh, accX, 0, 0, 0);
                accX = __builtin_amdgcn_mfma_f32_16x16x32_bf16(al, bh, accX, 0, 0, 0);
                accX = __builtin_amdgcn_mfma_f32_16x16x32_bf16(ah, bl, accX, 0, 0, 0);
            }
            #pragma unroll
            for (int r = 0; r < 4; ++r) {
                float v = accX[r];
                v = fmaxf(v, __shfl_xor(v, 1));
                v = fmaxf(v, __shfl_xor(v, 2));
                if ((lane & 3) == 0) {
                    const int oc = mt * 16 + (lane >> 4) * 4 + r;
                    const int pq2 = nt * 4 + (jcol >> 2);
                    s_s2[oc * 36 + pq2] = v + s_c2b[oc];
                }
            }
        }
    }
    __syncthreads();

    for (int i = tid; i < 576; i += 512)
        *(float4*)&s_ew[i * 4] = *(const float4*)&ew[i * 4];
    __syncthreads();

    {
        const int s  = tid >> 4;
        const int e0 = (tid & 15) * 4;
        float acc4[4];
        *(float4*)&acc4[0] = *(const float4*)&eb[e0];
        for (int f = 0; f < 36; ++f) {
            const float sv = s_s2[s * 36 + f];
            const float4 w0 = *(const float4*)&s_ew[f * 64 + e0];
            acc4[0] += sv * w0.x; acc4[1] += sv * w0.y;
            acc4[2] += sv * w0.z; acc4[3] += sv * w0.w;
        }
        float4 o0;
        o0.x = fmaxf(acc4[0], 0.0f); o0.y = fmaxf(acc4[1], 0.0f);
        o0.z = fmaxf(acc4[2], 0.0f); o0.w = fmaxf(acc4[3], 0.0f);
        *(float4*)&u[(size_t)p * 2048 + s * 64 + e0] = o0;
    }
}

// ---------------------------------------------------------------------------
// K2: full-MFMA attention + LN(64) + fused XL double-LN (r11 version, unchanged)
// ---------------------------------------------------------------------------
__global__ __launch_bounds__(512, 2) void k_attn(
    const float* __restrict__ u,
    const float* __restrict__ wq, const float* __restrict__ bq,
    const float* __restrict__ wk, const float* __restrict__ bk,
    const float* __restrict__ wv, const float* __restrict__ bv,
    const float* __restrict__ wo, const float* __restrict__ bo,
    const float* __restrict__ g1, const float* __restrict__ b1,
    const float* __restrict__ xg, const float* __restrict__ xb,
    unsigned short* __restrict__ Ah, unsigned short* __restrict__ Al)
{
    __shared__ __align__(16) unsigned short s_w[2][64 * 64];
    __shared__ __align__(16) float s_uf2[2][32 * 68];
    __shared__ __align__(16) unsigned short R1[2][12288];
    __shared__ __align__(16) unsigned short R2[2][5632];
    __shared__ float s_red[2][2][32][2];
    __shared__ float s_red2[2][2][4][2];

    const int g   = blockIdx.x;
    const int m   = g >> 7;
    const int tid = threadIdx.x;
    const int bh  = tid >> 8;
    const int t2  = tid & 255;
    const int b2  = (g & 127) * 2 + bh;
    const int l   = t2 & 63;
    const int w   = t2 >> 6;
    const int l15 = l & 15;
    const int lg  = l >> 4;

    float* s_uf = s_uf2[bh];
    unsigned short* qA_h = R1[bh];
    unsigned short* qA_l = R1[bh] + 3072;
    unsigned short* kB_h = R1[bh] + 6144;
    unsigned short* kB_l = R1[bh] + 9216;
    unsigned short* p_h  = R1[bh];
    unsigned short* p_l  = R1[bh] + 5120;
    unsigned short* vT_h = R2[bh];
    unsigned short* vT_l = R2[bh] + 2560;
    unsigned short* oA_h = R2[bh];
    unsigned short* oA_l = R2[bh] + 2816;

    {
        const int s = t2 >> 3, dq = (t2 & 7) * 8;
        const float* up = u + (size_t)(m * 256 + b2) * 2048 + s * 64 + dq;
        *(float4*)&s_uf[s * 68 + dq]     = *(const float4*)up;
        *(float4*)&s_uf[s * 68 + dq + 4] = *(const float4*)(up + 4);
    }

    const int wn   = tid & 63;
    const int wkq8 = tid >> 6;
    float wreg[8];

    #define LOADQKV(SRC)                                                          \
        {                                                                         \
            const float* sp = (SRC) + (size_t)m * 4096 + (wn >> 4) * 1024 + (wn & 15); \
            _Pragma("unroll")                                                     \
            for (int j = 0; j < 8; ++j) wreg[j] = sp[(wkq8 * 8 + j) * 16];        \
        }
    #define LOADO(SRC)                                                            \
        {                                                                         \
            const float* sp = (SRC) + (size_t)m * 4096 + wn;                      \
            _Pragma("unroll")                                                     \
            for (int j = 0; j < 8; ++j) wreg[j] = sp[(wkq8 * 8 + j) * 64];        \
        }
    #define WRITEW()                                                              \
        {                                                                         \
            _Pragma("unroll")                                                     \
            for (int j2 = 0; j2 < 4; ++j2) {                                      \
                const int d = wkq8 * 8 + j2 * 2;                                  \
                const float v0 = wreg[j2 * 2], v1 = wreg[j2 * 2 + 1];             \
                const unsigned short h0 = f2bf(v0), h1 = f2bf(v1);                \
                const unsigned short q0 = f2bf(v0 - bf2f(h0));                    \
                const unsigned short q1 = f2bf(v1 - bf2f(h1));                    \
                const int idx = wn * 64 + (((d >> 3) ^ (wn & 7)) << 3) + (d & 7); \
                *(unsigned*)&s_w[0][idx] = (unsigned)h0 | ((unsigned)h1 << 16);   \
                *(unsigned*)&s_w[1][idx] = (unsigned)q0 | ((unsigned)q1 << 16);   \
            }                                                                     \
        }

    LOADQKV(wq);
    __syncthreads();
    WRITEW();

    short8v uh[2][2], ul[2][2];
    #pragma unroll
    for (int mf = 0; mf < 2; ++mf)
        #pragma unroll
        for (int ks = 0; ks < 2; ++ks) {
            const float* pb = &s_uf[(mf * 16 + l15) * 68 + (ks * 4 + lg) * 8];
            float xv[8];
            *(float4*)&xv[0] = *(const float4*)pb;
            *(float4*)&xv[4] = *(const float4*)(pb + 4);
            short8v hh, ll;
            #pragma unroll
            for (int j = 0; j < 8; ++j) {
                const unsigned short h = f2bf(xv[j]);
                hh[j] = (short)h;
                ll[j] = (short)f2bf(xv[j] - bf2f(h));
            }
            uh[mf][ks] = hh; ul[mf][ks] = ll;
        }
    __syncthreads();

    #define PROJ(BIAS, MODE)                                                      \
        {                                                                         \
            short8v wbh[2], wbl[2];                                               \
            const int bn = w * 16 + l15;                                          \
            _Pragma("unroll")                                                     \
            for (int ks = 0; ks < 2; ++ks) {                                      \
                const int off = bn * 64 + (((ks * 4 + lg) ^ (bn & 7)) << 3);      \
                wbh[ks] = *(const short8v*)&s_w[0][off];                          \
                wbl[ks] = *(const short8v*)&s_w[1][off];                          \
            }                                                                     \
            const float bias_v = (BIAS)[m * 64 + bn];                             \
            f32x4 a0 = {0,0,0,0}, a1 = {0,0,0,0};                                 \
            _Pragma("unroll")                                                     \
            for (int ks = 0; ks < 2; ++ks) {                                      \
                MFMA3(a0, uh[0][ks], ul[0][ks], wbh[ks], wbl[ks]);                \
                MFMA3(a1, uh[1][ks], ul[1][ks], wbh[ks], wbl[ks]);                \
            }                                                                     \
            _Pragma("unroll")                                                     \
            for (int mf = 0; mf < 2; ++mf) {                                      \
                const f32x4 av = mf ? a1 : a0;                                    \
                _Pragma("unroll")                                                 \
                for (int r = 0; r < 4; ++r) {                                     \
                    const float val = av[r] + bias_v;                             \
                    const unsigned short hh = f2bf(val);                          \
                    const unsigned short lo = f2bf(val - bf2f(hh));               \
                    const int srow = mf * 16 + lg * 4 + r;                        \
                    if ((MODE) == 0) { const int ix = w * 768 + srow * 24 + l15;  \
                        qA_h[ix] = hh; qA_l[ix] = lo; }                           \
                    else if ((MODE) == 1) { const int ix = w * 768 + srow * 24 + l15; \
                        kB_h[ix] = hh; kB_l[ix] = lo; }                           \
                    else { const int ix = w * 640 + l15 * 40 + srow;              \
                        vT_h[ix] = hh; vT_l[ix] = lo; }                           \
                }                                                                 \
            }                                                                     \
        }

    PROJ(bq, 0);
    LOADQKV(wk);
    __syncthreads();
    WRITEW();
    __syncthreads();

    PROJ(bk, 1);
    LOADQKV(wv);
    __syncthreads();
    WRITEW();
    __syncthreads();

    PROJ(bv, 2);
    LOADO(wo);
    __syncthreads();
    WRITEW();
    __syncthreads();

    float pvreg[2][2][4];
    {
        const short8v zz = {0,0,0,0,0,0,0,0};
        short8v qh[2], ql[2], kh[2], kl[2];
        const bool kreal = (lg < 2);
        #pragma unroll
        for (int mf = 0; mf < 2; ++mf) {
            if (kreal) {
                const int ia = w * 768 + (mf * 16 + l15) * 24 + lg * 8;
                qh[mf] = *(const short8v*)&qA_h[ia];
                ql[mf] = *(const short8v*)&qA_l[ia];
                kh[mf] = *(const short8v*)&kB_h[ia];
                kl[mf] = *(const short8v*)&kB_l[ia];
            } else { qh[mf] = zz; ql[mf] = zz; kh[mf] = zz; kl[mf] = zz; }
        }
        f32x4 sc[2][2];
        #pragma unroll
        for (int mf = 0; mf < 2; ++mf)
            #pragma unroll
            for (int nf = 0; nf < 2; ++nf) {
                sc[mf][nf] = (f32x4){0,0,0,0};
                MFMA3(sc[mf][nf], qh[mf], ql[mf], kh[nf], kl[nf]);
            }
        #pragma unroll
        for (int mf = 0; mf < 2; ++mf)
            #pragma unroll
            for (int r = 0; r < 4; ++r) {
                const float v0 = sc[mf][0][r] * 0.25f;
                const float v1 = sc[mf][1][r] * 0.25f;
                float mx = fmaxf(v0, v1);
                mx = fmaxf(mx, __shfl_xor(mx, 1));
                mx = fmaxf(mx, __shfl_xor(mx, 2));
                mx = fmaxf(mx, __shfl_xor(mx, 4));
                mx = fmaxf(mx, __shfl_xor(mx, 8));
                const float e0 = expf(v0 - mx), e1 = expf(v1 - mx);
                float sm = e0 + e1;
                sm += __shfl_xor(sm, 1);
                sm += __shfl_xor(sm, 2);
                sm += __shfl_xor(sm, 4);
                sm += __shfl_xor(sm, 8);
                const float inv = 1.0f / sm;
                pvreg[mf][0][r] = e0 * inv;
                pvreg[mf][1][r] = e1 * inv;
            }
    }
    __syncthreads();

    #pragma unroll
    for (int mf = 0; mf < 2; ++mf)
        #pragma unroll
        for (int nf = 0; nf < 2; ++nf)
            #pragma unroll
            for (int r = 0; r < 4; ++r) {
                const int srow = mf * 16 + lg * 4 + r;
                const int tt = nf * 16 + l15;
                const int ix = w * 1280 + srow * 40 + tt;
                const float val = pvreg[mf][nf][r];
                const unsigned short hh = f2bf(val);
                p_h[ix] = hh;
                p_l[ix] = f2bf(val - bf2f(hh));
            }
    __syncthreads();

    f32x4 ov[2];
    {
        short8v ph[2], pl[2], vh_, vl_;
        #pragma unroll
        for (int mf = 0; mf < 2; ++mf) {
            const int ix = w * 1280 + (mf * 16 + l15) * 40 + lg * 8;
            ph[mf] = *(const short8v*)&p_h[ix];
            pl[mf] = *(const short8v*)&p_l[ix];
        }
        const int iv = w * 640 + l15 * 40 + lg * 8;
        vh_ = *(const short8v*)&vT_h[iv];
        vl_ = *(const short8v*)&vT_l[iv];
        #pragma unroll
        for (int mf = 0; mf < 2; ++mf) {
            ov[mf] = (f32x4){0,0,0,0};
            MFMA3(ov[mf], ph[mf], pl[mf], vh_, vl_);
        }
    }
    __syncthreads();

    #pragma unroll
    for (int mf = 0; mf < 2; ++mf)
        #pragma unroll
        for (int r = 0; r < 4; ++r) {
            const int srow = mf * 16 + lg * 4 + r;
            const int dd = w * 16 + l15;
            const int ix = srow * 88 + dd;
            const float val = ov[mf][r];
            const unsigned short hh = f2bf(val);
            oA_h[ix] = hh;
            oA_l[ix] = f2bf(val - bf2f(hh));
        }
    __syncthreads();

    const int mfA = w >> 1;
    const int nfb = (w & 1) * 2;
    float x[2][4];
    {
        short8v oh[2], ol[2];
        #pragma unroll
        for (int ks = 0; ks < 2; ++ks) {
            const int ix = (mfA * 16 + l15) * 88 + (ks * 4 + lg) * 8;
            oh[ks] = *(const short8v*)&oA_h[ix];
            ol[ks] = *(const short8v*)&oA_l[ix];
        }
        #pragma unroll
        for (int nfi = 0; nfi < 2; ++nfi) {
            const int n = (nfb + nfi) * 16 + l15;
            f32x4 xe = {0,0,0,0};
            #pragma unroll
            for (int ks = 0; ks < 2; ++ks) {
                const int off = n * 64 + (((ks * 4 + lg) ^ (n & 7)) << 3);
                const short8v wbh = *(const short8v*)&s_w[0][off];
                const short8v wbl = *(const short8v*)&s_w[1][off];
                MFMA3(xe, oh[ks], ol[ks], wbh, wbl);
            }
            const int e = n;
            const float bo_v = bo[m * 64 + e];
            #pragma unroll
            for (int r = 0; r < 4; ++r) {
                const int srow = mfA * 16 + lg * 4 + r;
                x[nfi][r] = xe[r] + bo_v + s_uf[srow * 68 + e];
            }
        }
    }
    #pragma unroll
    for (int r = 0; r < 4; ++r) {
        float s1 = x[0][r] + x[1][r];
        float s2 = x[0][r] * x[0][r] + x[1][r] * x[1][r];
        s1 += __shfl_xor(s1, 1); s2 += __shfl_xor(s2, 1);
        s1 += __shfl_xor(s1, 2); s2 += __shfl_xor(s2, 2);
        s1 += __shfl_xor(s1, 4); s2 += __shfl_xor(s2, 4);
        s1 += __shfl_xor(s1, 8); s2 += __shfl_xor(s2, 8);
        if (l15 == 0) {
            const int srow = mfA * 16 + lg * 4 + r;
            s_red[bh][w & 1][srow][0] = s1;
            s_red[bh][w & 1][srow][1] = s2;
        }
    }
    __syncthreads();

    float q2[2][4];
    #pragma unroll
    for (int r = 0; r < 4; ++r) {
        const int srow = mfA * 16 + lg * 4 + r;
        const float sum = s_red[bh][0][srow][0] + s_red[bh][1][srow][0];
        const float ssq = s_red[bh][0][srow][1] + s_red[bh][1][srow][1];
        const float mean = sum * (1.0f / 64.0f);
        const float var = fmaxf(ssq * (1.0f / 64.0f) - mean * mean, 0.0f);
        const float inv = rsqrtf(var + LN_EPS);
        #pragma unroll
        for (int nfi = 0; nfi < 2; ++nfi) {
            const int e = (nfb + nfi) * 16 + l15;
            const float y = (x[nfi][r] - mean) * inv * g1[e] + b1[e];
            q2[nfi][r] = 2.0f * y;
        }
    }

    #pragma unroll
    for (int L = 0; L < 2; ++L) {
        float ls = 0.0f, lq = 0.0f;
        #pragma unroll
        for (int nfi = 0; nfi < 2; ++nfi)
            #pragma unroll
            for (int r = 0; r < 4; ++r) { ls += q2[nfi][r]; lq += q2[nfi][r] * q2[nfi][r]; }
        ls += __shfl_xor(ls, 1);  lq += __shfl_xor(lq, 1);
        ls += __shfl_xor(ls, 2);  lq += __shfl_xor(lq, 2);
        ls += __shfl_xor(ls, 4);  lq += __shfl_xor(lq, 4);
        ls += __shfl_xor(ls, 8);  lq += __shfl_xor(lq, 8);
        ls += __shfl_xor(ls, 16); lq += __shfl_xor(lq, 16);
        ls += __shfl_xor(ls, 32); lq += __shfl_xor(lq, 32);
        if (l == 0) { s_red2[bh][L][w][0] = ls; s_red2[bh][L][w][1] = lq; }
        __syncthreads();
        const float sum = s_red2[bh][L][0][0] + s_red2[bh][L][1][0]
                        + s_red2[bh][L][2][0] + s_red2[bh][L][3][0];
        const float ssq = s_red2[bh][L][0][1] + s_red2[bh][L][1][1]
                        + s_red2[bh][L][2][1] + s_red2[bh][L][3][1];
        const float mean = sum * (1.0f / 2048.0f);
        const float var = fmaxf(ssq * (1.0f / 2048.0f) - mean * mean, 0.0f);
        const float inv = rsqrtf(var + LN_EPS);
        #pragma unroll
        for (int nfi = 0; nfi < 2; ++nfi)
            #pragma unroll
            for (int r = 0; r < 4; ++r) {
                const int srow = mfA * 16 + lg * 4 + r;
                const int e = (nfb + nfi) * 16 + l15;
                const int col = srow * 64 + e;
                const float z = (q2[nfi][r] - mean) * inv * xg[L * 2048 + col] + xb[L * 2048 + col];
                q2[nfi][r] = (L == 0) ? 2.0f * z : z;
            }
    }

    #pragma unroll
    for (int nfi = 0; nfi < 2; ++nfi)
        #pragma unroll
        for (int r = 0; r < 4; ++r) {
            const int srow = mfA * 16 + lg * 4 + r;
            const int e = (nfb + nfi) * 16 + l15;
            const int col = srow * 64 + e;
            const float val = q2[nfi][r];
            const unsigned short hh = f2bf(val);
            const size_t addr = ((size_t)(m * 64 + (col >> 5)) * 256 + b2) * 32 + (col & 31);
            Ah[addr] = hh;
            Al[addr] = f2bf(val - bf2f(hh));
        }
}

// ---------------------------------------------------------------------------
// K4: fl1 MFMA GEMM, 3-term bf16 hi/lo split (unchanged)
// ---------------------------------------------------------------------------
__global__ __launch_bounds__(512) void k_fl1(
    const unsigned short* __restrict__ Ah,
    const unsigned short* __restrict__ Al,
    const float* __restrict__ W,
    float* __restrict__ part)
{
    __shared__ __align__(16) unsigned short s_wh[128 * 64];
    __shared__ __align__(16) unsigned short s_wl[128 * 64];

    const int nb  = blockIdx.x;
    const int kb  = blockIdx.y;
    const int tid = threadIdx.x;
    const int lane = tid & 63;
    const int wid  = tid >> 6;
    const int wm = wid >> 1;
    const int wn = wid & 1;

    const int sn = tid & 127;
    const int sq = tid >> 7;
    const int k0 = kb * 512;

    f32x4 acc[4][4];
    #pragma unroll
    for (int i = 0; i < 4; ++i)
        #pragma unroll
        for (int j = 0; j < 4; ++j)
            acc[i][j] = (f32x4){0.0f, 0.0f, 0.0f, 0.0f};

    float wreg[16];
    {
        const float* wp = W + (size_t)(k0 + sq * 16) * 512 + nb * 128 + sn;
        #pragma unroll
        for (int j = 0; j < 16; ++j) wreg[j] = wp[(size_t)j * 512];
    }

    const int hsn = sn & 7;
    const int wbase = sn * 64;
    const int wo0 = (((sq * 2) ^ hsn) << 3);
    const int wo1 = (((sq * 2 + 1) ^ hsn) << 3);

    for (int tt = 0; tt < 8; ++tt) {
        __syncthreads();
        {
            short8v h0, h1, l0, l1;
            #pragma unroll
            for (int j = 0; j < 8; ++j) {
                const unsigned short ha = f2bf(wreg[j]);
                const unsigned short hb = f2bf(wreg[j + 8]);
                h0[j] = (short)ha;
                h1[j] = (short)hb;
                l0[j] = (short)f2bf(wreg[j] - bf2f(ha));
                l1[j] = (short)f2bf(wreg[j + 8] - bf2f(hb));
            }
            *(short8v*)&s_wh[wbase + wo0] = h0;
            *(short8v*)&s_wh[wbase + wo1] = h1;
            *(short8v*)&s_wl[wbase + wo0] = l0;
            *(short8v*)&s_wl[wbase + wo1] = l1;
        }
        if (tt < 7) {
            const float* wp = W + (size_t)(k0 + (tt + 1) * 64 + sq * 16) * 512 + nb * 128 + sn;
            #pragma unroll
            for (int j = 0; j < 16; ++j) wreg[j] = wp[(size_t)j * 512];
        }
        __syncthreads();

        #pragma unroll
        for (int ks = 0; ks < 2; ++ks) {
            const int ktile = (k0 >> 5) + tt * 2 + ks;
            const size_t abase = ((size_t)ktile * 256 + wm * 64 + (lane & 15)) * 32
                               + (lane >> 4) * 8;
            short8v ahf[4], alf[4];
            #pragma unroll
            for (int mf = 0; mf < 4; ++mf) {
                ahf[mf] = *(const short8v*)&Ah[abase + (size_t)mf * 512];
                alf[mf] = *(const short8v*)&Al[abase + (size_t)mf * 512];
            }
            short8v bhf[4], blf[4];
            #pragma unroll
            for (int nf = 0; nf < 4; ++nf) {
                const int n = wn * 64 + nf * 16 + (lane & 15);
                const int q = ks * 4 + (lane >> 4);
                const int baddr = n * 64 + ((q ^ (n & 7)) << 3);
                bhf[nf] = *(const short8v*)&s_wh[baddr];
                blf[nf] = *(const short8v*)&s_wl[baddr];
            }
            #pragma unroll
            for (int mf = 0; mf < 4; ++mf)
                #pragma unroll
                for (int nf = 0; nf < 4; ++nf) {
                    MFMA3(acc[mf][nf], ahf[mf], alf[mf], bhf[nf], blf[nf]);
                }
        }
    }

    float* pp = part + (size_t)kb * 131072 + (size_t)nb * 128;
    const int r0 = (lane >> 4) * 4;
    const int c  = lane & 15;
    #pragma unroll
    for (int mf = 0; mf < 4; ++mf) {
        const int row = wm * 64 + mf * 16 + r0;
        #pragma unroll
        for (int nf = 0; nf < 4; ++nf) {
            const int col = wn * 64 + nf * 16 + c;
            #pragma unroll
            for (int r = 0; r < 4; ++r)
                pp[(size_t)(row + r) * 512 + col] = acc[mf][nf][r];
        }
    }
}

// ---------------------------------------------------------------------------
// K5: fused tail — fl1 reduce+bias+relu -> fl2 -> fl3 (unchanged)
// ---------------------------------------------------------------------------
__global__ __launch_bounds__(256) void k_tail(
    const float* __restrict__ part, const float* __restrict__ fb1,
    const float* __restrict__ w2,   const float* __restrict__ fb2,
    const float* __restrict__ w3,   const float* __restrict__ fb3,
    float* __restrict__ out)
{
    __shared__ float s_u1[512];
    __shared__ float s_u2[128];
    const int r = blockIdx.x, tid = threadIdx.x;

    if (tid < 128) {
        const int i4 = r * 512 + tid * 4;
        float4 s = *(const float4*)&fb1[tid * 4];
        for (int ks = 0; ks < 64; ++ks) {
            const float4 p = *(const float4*)&part[(size_t)ks * 131072 + i4];
            s.x += p.x; s.y += p.y; s.z += p.z; s.w += p.w;
        }
        s.x = fmaxf(s.x, 0.0f); s.y = fmaxf(s.y, 0.0f);
        s.z = fmaxf(s.z, 0.0f); s.w = fmaxf(s.w, 0.0f);
        *(float4*)&s_u1[tid * 4] = s;
    }
    __syncthreads();

    if (tid < 128) {
        float acc = fb2[tid];
        for (int k = 0; k < 512; k++) acc += s_u1[k] * w2[k * 128 + tid];
        s_u2[tid] = fmaxf(acc, 0.0f);
    }
    __syncthreads();

    if (tid < 25) {
        float acc = fb3[tid];
        for (int k = 0; k < 128; k++) acc += s_u2[k] * w3[k * 25 + tid];
        out[r * 25 + tid] = acc;
    }
}

// ---------------------------------------------------------------------------
extern "C" void kernel_launch(void* const* d_in, const int* in_sizes, int n_in,
                              void* d_out, int out_size, void* d_ws, size_t ws_size,
                              hipStream_t stream)
{
    const float* t      = (const float*)d_in[0];
    const float* c1w    = (const float*)d_in[1];
    const float* c1b    = (const float*)d_in[2];
    const float* c2w    = (const float*)d_in[3];
    const float* c2b    = (const float*)d_in[4];
    const float* ew     = (const float*)d_in[5];
    const float* eb     = (const float*)d_in[6];
    const float* mh_wq  = (const float*)d_in[7];
    const float* mh_bq  = (const float*)d_in[8];
    const float* mh_wk  = (const float*)d_in[9];
    const float* mh_bk  = (const float*)d_in[10];
    const float* mh_wv  = (const float*)d_in[11];
    const float* mh_bv  = (const float*)d_in[12];
    const float* mh_wo  = (const float*)d_in[13];
    const float* mh_bo  = (const float*)d_in[14];
    const float* ln1_g  = (const float*)d_in[15];
    const float* ln1_b  = (const float*)d_in[16];
    // d_in[17..24]: XL attention weights -- dead code in the reference, unused
    const float* xln_g  = (const float*)d_in[25];
    const float* xln_b  = (const float*)d_in[26];
    const float* fl1_w  = (const float*)d_in[27];
    const float* fl1_b  = (const float*)d_in[28];
    const float* fl2_w  = (const float*)d_in[29];
    const float* fl2_b  = (const float*)d_in[30];
    const float* fl3_w  = (const float*)d_in[31];
    const float* fl3_b  = (const float*)d_in[32];
    (void)in_sizes; (void)n_in; (void)out_size; (void)ws_size;

    float* U   = (float*)d_ws;                 // conv u (f32); later PART
    float* U2  = U + 8388608;                  // Ah/Al
    unsigned short* Ah = (unsigned short*)U2;
    unsigned short* Al = Ah + 8388608;
    float* PART = U;                           // u dead after k_attn
    float* out  = (float*)d_out;

    k_conv<<<4096, 512, 0, stream>>>(t, c1w, c1b, c2w, c2b, ew, eb, U);
    k_attn<<<2048, 512, 0, stream>>>(U, mh_wq, mh_bq, mh_wk, mh_bk, mh_wv, mh_bv,
                                     mh_wo, mh_bo, ln1_g, ln1_b, xln_g, xln_b,
                                     Ah, Al);
    k_fl1<<<dim3(4, 64), 512, 0, stream>>>(Ah, Al, fl1_w, PART);
    k_tail<<<256, 256, 0, stream>>>(PART, fl1_b, fl2_w, fl2_b, fl3_w, fl3_b, out);
}

// Round 13
// 266.332 us; speedup vs baseline: 1.0402x; 1.0402x over previous
//
#include <hip/hip_runtime.h>
#include <hip/hip_bf16.h>
#include <math.h>

#define LN_EPS 1e-5f

typedef __attribute__((ext_vector_type(8))) short short8v;
typedef __attribute__((ext_vector_type(4))) float f32x4;

static __device__ __forceinline__ unsigned short f2bf(float x) {
    unsigned u = __float_as_uint(x);
    u += 0x7fffu + ((u >> 16) & 1u);
    return (unsigned short)(u >> 16);
}
static __device__ __forceinline__ float bf2f(unsigned short h) {
    return __uint_as_float(((unsigned)h) << 16);
}

#define MFMA3(ACC, AH, AL, BH, BL)                                          \
    ACC = __builtin_amdgcn_mfma_f32_16x16x32_bf16(AH, BH, ACC, 0, 0, 0);    \
    ACC = __builtin_amdgcn_mfma_f32_16x16x32_bf16(AL, BH, ACC, 0, 0, 0);    \
    ACC = __builtin_amdgcn_mfma_f32_16x16x32_bf16(AH, BL, ACC, 0, 0, 0);

// ---------------------------------------------------------------------------
// K1: FUSED per-patch pipeline: conv1+pool (f32) -> conv2 (MFMA) + shfl-pool
//     -> expansion -> 4-head attention (MFMA) + LN(64) + XL double-LN,
//     emitting Ah/Al directly. Block = patch p (m = p>>8, b2 = p&255).
// 512 threads (8 waves), 77.3 KB LDS -> 2 blocks/CU. conv part = r10 layout
// (best measured); attn compute on waves 0-3 (guards), weight staging on all.
// ---------------------------------------------------------------------------
__global__ __launch_bounds__(512, 4) void k_fused(
    const float* __restrict__ t,
    const float* __restrict__ c1w, const float* __restrict__ c1b,
    const float* __restrict__ c2w, const float* __restrict__ c2b,
    const float* __restrict__ ew,  const float* __restrict__ eb,
    const float* __restrict__ wq, const float* __restrict__ bq,
    const float* __restrict__ wk, const float* __restrict__ bk,
    const float* __restrict__ wv, const float* __restrict__ bv,
    const float* __restrict__ wo, const float* __restrict__ bo,
    const float* __restrict__ g1, const float* __restrict__ b1,
    const float* __restrict__ xg, const float* __restrict__ xb,
    unsigned short* __restrict__ Ah, unsigned short* __restrict__ Al)
{
    __shared__ __align__(16) unsigned short s_W2[2][9216];   // 36864 B
    __shared__ __align__(16) unsigned short s_p1[14400];     // 28800 B
    __shared__ __align__(16) float s_s2[1152];               // 4608 B (+reds alias)
    __shared__ __align__(16) float s_uf[32 * 68];            // 8704 B
    __shared__ float s_c2b[32];

    // conv-phase aliases
    float* s_x  = (float*)s_W2;           // [32][33] phase 0/A
    unsigned short* s_wh  = s_W2[0];      // conv W hi
    unsigned short* s_wl  = s_W2[1];      // conv W lo
    unsigned short* s_p1h = s_p1;         // [4][225][8]
    unsigned short* s_p1l = s_p1 + 7200;
    float* s_ew = (float*)s_p1;           // phase C (p1 dead)
    // attn-phase aliases (all regions dead by the time they're reused)
    unsigned short* aw_h = s_W2[0];           // attn weight hi [64*64]
    unsigned short* aw_l = s_W2[0] + 4096;    // attn weight lo
    unsigned short* R1   = s_p1;
    unsigned short* R2   = s_W2[1];
    unsigned short* qA_h = R1;
    unsigned short* qA_l = R1 + 3072;
    unsigned short* kB_h = R1 + 6144;
    unsigned short* kB_l = R1 + 9216;
    unsigned short* p_h  = R1;
    unsigned short* p_l  = R1 + 5120;
    unsigned short* vT_h = R2;
    unsigned short* vT_l = R2 + 2560;
    unsigned short* oA_h = R2;
    unsigned short* oA_l = R2 + 2816;
    float* s_redf = s_s2;                 // [0..127] LN64, [128..143] XL-LN

    const int p   = blockIdx.x;
    const int tid = threadIdx.x;      // 0..511

    // =================== conv section (r10, unchanged math) ===================
    const int b = p >> 4, tile = p & 15, tr = tile >> 2, tc = tile & 3;
    const float* tp = t + (size_t)b * 128 * 128 + (size_t)tr * 32 * 128 + tc * 32;
    for (int i = tid; i < 1024; i += 512) {
        const int r = i >> 5, c = i & 31;
        s_x[r * 33 + c] = tp[r * 128 + c] * (1.0f / 255.0f);
    }
    if (tid < 32) s_c2b[tid] = c2b[tid];
    __syncthreads();

    // ---- phase A: conv1 (1->32, 3x3) + pool -> p1 bf16 hi/lo ----
    if ((tid & 255) < 225) {
        const int pos  = tid & 255;
        const int half = tid >> 8;
        const int pi = pos / 15, pj = pos % 15;
        float xw[16];
        #pragma unroll
        for (int r = 0; r < 4; ++r)
            #pragma unroll
            for (int c = 0; c < 4; ++c)
                xw[r * 4 + c] = s_x[(2 * pi + r) * 33 + (2 * pj + c)];
        #pragma unroll
        for (int og2 = 0; og2 < 2; ++og2) {
            const int og = half * 2 + og2;
            short8v hb, lb;
            #pragma unroll
            for (int o = 0; o < 8; ++o) {
                const int oc = og * 8 + o;
                float w[9];
                #pragma unroll
                for (int j = 0; j < 9; ++j) w[j] = c1w[oc * 9 + j];
                float mx = -3.0e38f;
                #pragma unroll
                for (int a = 0; a < 2; ++a)
                    #pragma unroll
                    for (int bb = 0; bb < 2; ++bb) {
                        float s = xw[(a + 0) * 4 + bb + 0] * w[0]
                                + xw[(a + 0) * 4 + bb + 1] * w[1]
                                + xw[(a + 0) * 4 + bb + 2] * w[2]
                                + xw[(a + 1) * 4 + bb + 0] * w[3]
                                + xw[(a + 1) * 4 + bb + 1] * w[4]
                                + xw[(a + 1) * 4 + bb + 2] * w[5]
                                + xw[(a + 2) * 4 + bb + 0] * w[6]
                                + xw[(a + 2) * 4 + bb + 1] * w[7]
                                + xw[(a + 2) * 4 + bb + 2] * w[8];
                        mx = fmaxf(mx, s);
                    }
                const float val = mx + c1b[oc];
                const unsigned short h = f2bf(val);
                hb[o] = (short)h;
                lb[o] = (short)f2bf(val - bf2f(h));
            }
            *(short8v*)&s_p1h[og * 1800 + pos * 8] = hb;
            *(short8v*)&s_p1l[og * 1800 + pos * 8] = lb;
        }
    }
    __syncthreads();

    // ---- stage c2w -> [ks][kg][oc][8] (overwrites s_x) ----
    {
        const int oc  = tid >> 4;
        const int sub = tid & 15;
        const int kg  = sub >> 2;
        const int off = (sub * 2) & 7;
        const float* wp = c2w + oc * 288 + sub * 18;
        float wf[18];
        #pragma unroll
        for (int j = 0; j < 9; ++j)
            *(float2*)&wf[j * 2] = *(const float2*)&wp[j * 2];
        #pragma unroll
        for (int ks = 0; ks < 9; ++ks) {
            const float v0 = wf[ks];
            const float v1 = wf[9 + ks];
            const unsigned short h0 = f2bf(v0), h1 = f2bf(v1);
            const unsigned short l0 = f2bf(v0 - bf2f(h0));
            const unsigned short l1 = f2bf(v1 - bf2f(h1));
            const int idx = ks * 1024 + kg * 256 + oc * 8 + off;
            *(unsigned*)&s_wh[idx] = (unsigned)h0 | ((unsigned)h1 << 16);
            *(unsigned*)&s_wl[idx] = (unsigned)l0 | ((unsigned)l1 << 16);
        }
    }
    __syncthreads();

    // ---- phase B: conv2 via MFMA + in-register 2x2 pool ----
    {
        const int lane = tid & 63;
        const int w8   = tid >> 6;
        const int jcol = lane & 15;
        const int lg   = lane >> 4;

        {
            const int nt = w8;
            const int n = nt * 16 + jcol;
            const int pq = n >> 2, w4 = n & 3;
            const int pi = pq / 6, pj = pq - pi * 6;
            const int rbase = 2 * pi + (w4 >> 1);
            const int cbase = 2 * pj + (w4 & 1);

            f32x4 acc0 = {0,0,0,0}, acc1 = {0,0,0,0};
            #pragma unroll
            for (int ks = 0; ks < 9; ++ks) {
                const int dr = ks / 3, dc = ks - dr * 3;
                const int ab = ks * 1024 + lg * 256 + jcol * 8;
                const short8v ah0 = *(const short8v*)&s_wh[ab];
                const short8v ah1 = *(const short8v*)&s_wh[ab + 128];
                const short8v al0 = *(const short8v*)&s_wl[ab];
                const short8v al1 = *(const short8v*)&s_wl[ab + 128];
                const int wpos = (rbase + dr) * 15 + (cbase + dc);
                const int boff = lg * 1800 + wpos * 8;
                const short8v bh = *(const short8v*)&s_p1h[boff];
                const short8v bl = *(const short8v*)&s_p1l[boff];
                acc0 = __builtin_amdgcn_mfma_f32_16x16x32_bf16(ah0, bh, acc0, 0, 0, 0);
                acc0 = __builtin_amdgcn_mfma_f32_16x16x32_bf16(al0, bh, acc0, 0, 0, 0);
                acc0 = __builtin_amdgcn_mfma_f32_16x16x32_bf16(ah0, bl, acc0, 0, 0, 0);
                acc1 = __builtin_amdgcn_mfma_f32_16x16x32_bf16(ah1, bh, acc1, 0, 0, 0);
                acc1 = __builtin_amdgcn_mfma_f32_16x16x32_bf16(al1, bh, acc1, 0, 0, 0);
                acc1 = __builtin_amdgcn_mfma_f32_16x16x32_bf16(ah1, bl, acc1, 0, 0, 0);
            }
            #pragma unroll
            for (int mt = 0; mt < 2; ++mt)
                #pragma unroll
                for (int r = 0; r < 4; ++r) {
                    float v = (mt == 0) ? acc0[r] : acc1[r];
                    v = fmaxf(v, __shfl_xor(v, 1));
                    v = fmaxf(v, __shfl_xor(v, 2));
                    if ((lane & 3) == 0) {
                        const int oc = mt * 16 + (lane >> 4) * 4 + r;
                        const int pq2 = nt * 4 + (jcol >> 2);
                        s_s2[oc * 36 + pq2] = v + s_c2b[oc];
                    }
                }
        }

        if (w8 < 2) {
            const int nt = 8;
            const int mt = w8;
            const int n = nt * 16 + jcol;
            const int pq = n >> 2, w4 = n & 3;
            const int pi = pq / 6, pj = pq - pi * 6;
            const int rbase = 2 * pi + (w4 >> 1);
            const int cbase = 2 * pj + (w4 & 1);

            f32x4 accX = {0,0,0,0};
            #pragma unroll
            for (int ks = 0; ks < 9; ++ks) {
                const int dr = ks / 3, dc = ks - dr * 3;
                const int ab = ks * 1024 + lg * 256 + jcol * 8 + mt * 128;
                const short8v ah = *(const short8v*)&s_wh[ab];
                const short8v al = *(const short8v*)&s_wl[ab];
                const int wpos = (rbase + dr) * 15 + (cbase + dc);
                const int boff = lg * 1800 + wpos * 8;
                const short8v bh = *(const short8v*)&s_p1h[boff];
                const short8v bl = *(const short8v*)&s_p1l[boff];
                accX = __builtin_amdgcn_mfma_f32_16x16x32_bf16(ah, bh, accX, 0, 0, 0);
                accX = __builtin_amdgcn_mfma_f32_16x16x32_bf16(al, bh, accX, 0, 0, 0);
                accX = __builtin_amdgcn_mfma_f32_16x16x32_bf16(ah, bl, accX, 0, 0, 0);
            }
            #pragma unroll
            for (int r = 0; r < 4; ++r) {
                float v = accX[r];
                v = fmaxf(v, __shfl_xor(v, 1));
                v = fmaxf(v, __shfl_xor(v, 2));
                if ((lane & 3) == 0) {
                    const int oc = mt * 16 + (lane >> 4) * 4 + r;
                    const int pq2 = nt * 4 + (jcol >> 2);
                    s_s2[oc * 36 + pq2] = v + s_c2b[oc];
                }
            }
        }
    }
    __syncthreads();

    // ---- stage ew (p1 region) + issue Wq loads (regs) ----
    const int m2 = p >> 8;
    const int b2 = p & 255;
    const int wn   = tid & 63;
    const int wkq8 = tid >> 6;
    float wreg[8];

    #define LOADQKV(SRC)                                                          \
        {                                                                         \
            const float* sp = (SRC) + (size_t)m2 * 4096 + (wn >> 4) * 1024 + (wn & 15); \
            _Pragma("unroll")                                                     \
            for (int j = 0; j < 8; ++j) wreg[j] = sp[(wkq8 * 8 + j) * 16];        \
        }
    #define LOADO(SRC)                                                            \
        {                                                                         \
            const float* sp = (SRC) + (size_t)m2 * 4096 + wn;                     \
            _Pragma("unroll")                                                     \
            for (int j = 0; j < 8; ++j) wreg[j] = sp[(wkq8 * 8 + j) * 64];        \
        }
    #define WRITEW()                                                              \
        {                                                                         \
            _Pragma("unroll")                                                     \
            for (int j2 = 0; j2 < 4; ++j2) {                                      \
                const int d = wkq8 * 8 + j2 * 2;                                  \
                const float v0 = wreg[j2 * 2], v1 = wreg[j2 * 2 + 1];             \
                const unsigned short h0 = f2bf(v0), h1 = f2bf(v1);                \
                const unsigned short q0 = f2bf(v0 - bf2f(h0));                    \
                const unsigned short q1 = f2bf(v1 - bf2f(h1));                    \
                const int idx = wn * 64 + (((d >> 3) ^ (wn & 7)) << 3) + (d & 7); \
                *(unsigned*)&aw_h[idx] = (unsigned)h0 | ((unsigned)h1 << 16);     \
                *(unsigned*)&aw_l[idx] = (unsigned)q0 | ((unsigned)q1 << 16);     \
            }                                                                     \
        }

    for (int i = tid; i < 576; i += 512)
        *(float4*)&s_ew[i * 4] = *(const float4*)&ew[i * 4];
    LOADQKV(wq);
    __syncthreads();

    // ---- phase C: expansion -> s_uf (no global round trip) ----
    {
        const int s  = tid >> 4;
        const int e0 = (tid & 15) * 4;
        float acc4[4];
        *(float4*)&acc4[0] = *(const float4*)&eb[e0];
        for (int f = 0; f < 36; ++f) {
            const float sv = s_s2[s * 36 + f];
            const float4 w0 = *(const float4*)&s_ew[f * 64 + e0];
            acc4[0] += sv * w0.x; acc4[1] += sv * w0.y;
            acc4[2] += sv * w0.z; acc4[3] += sv * w0.w;
        }
        float4 o0;
        o0.x = fmaxf(acc4[0], 0.0f); o0.y = fmaxf(acc4[1], 0.0f);
        o0.z = fmaxf(acc4[2], 0.0f); o0.w = fmaxf(acc4[3], 0.0f);
        *(float4*)&s_uf[s * 68 + e0] = o0;
    }
    __syncthreads();

    // =================== attn section (waves 0-3 compute) ===================
    const int l   = tid & 63;
    const int w   = tid >> 6;        // head (valid for tid<256)
    const int l15 = l & 15;
    const int lg  = l >> 4;

    WRITEW();                        // Wq -> aw (conv W dead)

    short8v uh[2][2], ul[2][2];
    if (tid < 256) {
        #pragma unroll
        for (int mf = 0; mf < 2; ++mf)
            #pragma unroll
            for (int ks = 0; ks < 2; ++ks) {
                const float* pb = &s_uf[(mf * 16 + l15) * 68 + (ks * 4 + lg) * 8];
                float xv[8];
                *(float4*)&xv[0] = *(const float4*)pb;
                *(float4*)&xv[4] = *(const float4*)(pb + 4);
                short8v hh, ll;
                #pragma unroll
                for (int j = 0; j < 8; ++j) {
                    const unsigned short h = f2bf(xv[j]);
                    hh[j] = (short)h;
                    ll[j] = (short)f2bf(xv[j] - bf2f(h));
                }
                uh[mf][ks] = hh; ul[mf][ks] = ll;
            }
    }
    __syncthreads();                 // Wq in LDS; uh built (s_uf stable)

    #define PROJ(BIAS, MODE)                                                      \
        if (tid < 256) {                                                          \
            short8v wbh[2], wbl[2];                                               \
            const int bn = w * 16 + l15;                                          \
            _Pragma("unroll")                                                     \
            for (int ks = 0; ks < 2; ++ks) {                                      \
                const int off = bn * 64 + (((ks * 4 + lg) ^ (bn & 7)) << 3);      \
                wbh[ks] = *(const short8v*)&aw_h[off];                            \
                wbl[ks] = *(const short8v*)&aw_l[off];                            \
            }                                                                     \
            const float bias_v = (BIAS)[m2 * 64 + bn];                            \
            f32x4 a0 = {0,0,0,0}, a1 = {0,0,0,0};                                 \
            _Pragma("unroll")                                                     \
            for (int ks = 0; ks < 2; ++ks) {                                      \
                MFMA3(a0, uh[0][ks], ul[0][ks], wbh[ks], wbl[ks]);                \
                MFMA3(a1, uh[1][ks], ul[1][ks], wbh[ks], wbl[ks]);                \
            }                                                                     \
            _Pragma("unroll")                                                     \
            for (int mf = 0; mf < 2; ++mf) {                                      \
                const f32x4 av = mf ? a1 : a0;                                    \
                _Pragma("unroll")                                                 \
                for (int r = 0; r < 4; ++r) {                                     \
                    const float val = av[r] + bias_v;                             \
                    const unsigned short hh = f2bf(val);                          \
                    const unsigned short lo = f2bf(val - bf2f(hh));               \
                    const int srow = mf * 16 + lg * 4 + r;                        \
                    if ((MODE) == 0) { const int ix = w * 768 + srow * 24 + l15;  \
                        qA_h[ix] = hh; qA_l[ix] = lo; }                           \
                    else if ((MODE) == 1) { const int ix = w * 768 + srow * 24 + l15; \
                        kB_h[ix] = hh; kB_l[ix] = lo; }                           \
                    else { const int ix = w * 640 + l15 * 40 + srow;              \
                        vT_h[ix] = hh; vT_l[ix] = lo; }                           \
                }                                                                 \
            }                                                                     \
        }

    PROJ(bq, 0);
    LOADQKV(wk);
    __syncthreads();
    WRITEW();
    __syncthreads();

    PROJ(bk, 1);
    LOADQKV(wv);
    __syncthreads();
    WRITEW();
    __syncthreads();

    PROJ(bv, 2);
    LOADO(wo);
    __syncthreads();
    WRITEW();                        // Wo -> aw
    __syncthreads();

    // ---- scores + in-register softmax ----
    float pvreg[2][2][4];
    if (tid < 256) {
        const short8v zz = {0,0,0,0,0,0,0,0};
        short8v qh[2], ql[2], kh[2], kl[2];
        const bool kreal = (lg < 2);
        #pragma unroll
        for (int mf = 0; mf < 2; ++mf) {
            if (kreal) {
                const int ia = w * 768 + (mf * 16 + l15) * 24 + lg * 8;
                qh[mf] = *(const short8v*)&qA_h[ia];
                ql[mf] = *(const short8v*)&qA_l[ia];
                kh[mf] = *(const short8v*)&kB_h[ia];
                kl[mf] = *(const short8v*)&kB_l[ia];
            } else { qh[mf] = zz; ql[mf] = zz; kh[mf] = zz; kl[mf] = zz; }
        }
        f32x4 sc[2][2];
        #pragma unroll
        for (int mf = 0; mf < 2; ++mf)
            #pragma unroll
            for (int nf = 0; nf < 2; ++nf) {
                sc[mf][nf] = (f32x4){0,0,0,0};
                MFMA3(sc[mf][nf], qh[mf], ql[mf], kh[nf], kl[nf]);
            }
        #pragma unroll
        for (int mf = 0; mf < 2; ++mf)
            #pragma unroll
            for (int r = 0; r < 4; ++r) {
                const float v0 = sc[mf][0][r] * 0.25f;
                const float v1 = sc[mf][1][r] * 0.25f;
                float mx = fmaxf(v0, v1);
                mx = fmaxf(mx, __shfl_xor(mx, 1));
                mx = fmaxf(mx, __shfl_xor(mx, 2));
                mx = fmaxf(mx, __shfl_xor(mx, 4));
                mx = fmaxf(mx, __shfl_xor(mx, 8));
                const float e0 = expf(v0 - mx), e1 = expf(v1 - mx);
                float sm = e0 + e1;
                sm += __shfl_xor(sm, 1);
                sm += __shfl_xor(sm, 2);
                sm += __shfl_xor(sm, 4);
                sm += __shfl_xor(sm, 8);
                const float inv = 1.0f / sm;
                pvreg[mf][0][r] = e0 * inv;
                pvreg[mf][1][r] = e1 * inv;
            }
    }
    __syncthreads();                 // qA/kB reads complete

    if (tid < 256) {
        #pragma unroll
        for (int mf = 0; mf < 2; ++mf)
            #pragma unroll
            for (int nf = 0; nf < 2; ++nf)
                #pragma unroll
                for (int r = 0; r < 4; ++r) {
                    const int srow = mf * 16 + lg * 4 + r;
                    const int tt = nf * 16 + l15;
                    const int ix = w * 1280 + srow * 40 + tt;
                    const float val = pvreg[mf][nf][r];
                    const unsigned short hh = f2bf(val);
                    p_h[ix] = hh;
                    p_l[ix] = f2bf(val - bf2f(hh));
                }
    }
    __syncthreads();

    // ---- PV ----
    f32x4 ov[2];
    if (tid < 256) {
        short8v ph[2], pl[2], vh_, vl_;
        #pragma unroll
        for (int mf = 0; mf < 2; ++mf) {
            const int ix = w * 1280 + (mf * 16 + l15) * 40 + lg * 8;
            ph[mf] = *(const short8v*)&p_h[ix];
            pl[mf] = *(const short8v*)&p_l[ix];
        }
        const int iv = w * 640 + l15 * 40 + lg * 8;
        vh_ = *(const short8v*)&vT_h[iv];
        vl_ = *(const short8v*)&vT_l[iv];
        #pragma unroll
        for (int mf = 0; mf < 2; ++mf) {
            ov[mf] = (f32x4){0,0,0,0};
            MFMA3(ov[mf], ph[mf], pl[mf], vh_, vl_);
        }
    }
    __syncthreads();                 // vT reads complete

    if (tid < 256) {
        #pragma unroll
        for (int mf = 0; mf < 2; ++mf)
            #pragma unroll
            for (int r = 0; r < 4; ++r) {
                const int srow = mf * 16 + lg * 4 + r;
                const int dd = w * 16 + l15;
                const int ix = srow * 88 + dd;
                const float val = ov[mf][r];
                const unsigned short hh = f2bf(val);
                oA_h[ix] = hh;
                oA_l[ix] = f2bf(val - bf2f(hh));
            }
    }
    __syncthreads();

    // ---- o-proj + bias + residual + LN(64) ----
    const int mfA = (w & 3) >> 1;
    const int nfb = (w & 1) * 2;
    float x[2][4];
    if (tid < 256) {
        short8v oh[2], ol[2];
        #pragma unroll
        for (int ks = 0; ks < 2; ++ks) {
            const int ix = (mfA * 16 + l15) * 88 + (ks * 4 + lg) * 8;
            oh[ks] = *(const short8v*)&oA_h[ix];
            ol[ks] = *(const short8v*)&oA_l[ix];
        }
        #pragma unroll
        for (int nfi = 0; nfi < 2; ++nfi) {
            const int n = (nfb + nfi) * 16 + l15;
            f32x4 xe = {0,0,0,0};
            #pragma unroll
            for (int ks = 0; ks < 2; ++ks) {
                const int off = n * 64 + (((ks * 4 + lg) ^ (n & 7)) << 3);
                const short8v wbh = *(const short8v*)&aw_h[off];
                const short8v wbl = *(const short8v*)&aw_l[off];
                MFMA3(xe, oh[ks], ol[ks], wbh, wbl);
            }
            const float bo_v = bo[m2 * 64 + n];
            #pragma unroll
            for (int r = 0; r < 4; ++r) {
                const int srow = mfA * 16 + lg * 4 + r;
                x[nfi][r] = xe[r] + bo_v + s_uf[srow * 68 + n];
            }
        }
        #pragma unroll
        for (int r = 0; r < 4; ++r) {
            float s1 = x[0][r] + x[1][r];
            float s2 = x[0][r] * x[0][r] + x[1][r] * x[1][r];
            s1 += __shfl_xor(s1, 1); s2 += __shfl_xor(s2, 1);
            s1 += __shfl_xor(s1, 2); s2 += __shfl_xor(s2, 2);
            s1 += __shfl_xor(s1, 4); s2 += __shfl_xor(s2, 4);
            s1 += __shfl_xor(s1, 8); s2 += __shfl_xor(s2, 8);
            if (l15 == 0) {
                const int srow = mfA * 16 + lg * 4 + r;
                s_redf[(w & 1) * 64 + srow * 2 + 0] = s1;
                s_redf[(w & 1) * 64 + srow * 2 + 1] = s2;
            }
        }
    }
    __syncthreads();

    float q2[2][4];
    if (tid < 256) {
        #pragma unroll
        for (int r = 0; r < 4; ++r) {
            const int srow = mfA * 16 + lg * 4 + r;
            const float sum = s_redf[srow * 2 + 0] + s_redf[64 + srow * 2 + 0];
            const float ssq = s_redf[srow * 2 + 1] + s_redf[64 + srow * 2 + 1];
            const float mean = sum * (1.0f / 64.0f);
            const float var = fmaxf(ssq * (1.0f / 64.0f) - mean * mean, 0.0f);
            const float inv = rsqrtf(var + LN_EPS);
            #pragma unroll
            for (int nfi = 0; nfi < 2; ++nfi) {
                const int e = (nfb + nfi) * 16 + l15;
                const float y = (x[nfi][r] - mean) * inv * g1[e] + b1[e];
                q2[nfi][r] = 2.0f * y;
            }
        }
    }

    // ---- fused XL double-LN over the 2048 row ----
    #pragma unroll
    for (int L = 0; L < 2; ++L) {
        if (tid < 256) {
            float ls = 0.0f, lq = 0.0f;
            #pragma unroll
            for (int nfi = 0; nfi < 2; ++nfi)
                #pragma unroll
                for (int r = 0; r < 4; ++r) { ls += q2[nfi][r]; lq += q2[nfi][r] * q2[nfi][r]; }
            ls += __shfl_xor(ls, 1);  lq += __shfl_xor(lq, 1);
            ls += __shfl_xor(ls, 2);  lq += __shfl_xor(lq, 2);
            ls += __shfl_xor(ls, 4);  lq += __shfl_xor(lq, 4);
            ls += __shfl_xor(ls, 8);  lq += __shfl_xor(lq, 8);
            ls += __shfl_xor(ls, 16); lq += __shfl_xor(lq, 16);
            ls += __shfl_xor(ls, 32); lq += __shfl_xor(lq, 32);
            if (l == 0) {
                s_redf[128 + L * 8 + w * 2 + 0] = ls;
                s_redf[128 + L * 8 + w * 2 + 1] = lq;
            }
        }
        __syncthreads();
        if (tid < 256) {
            const float sum = s_redf[128 + L * 8 + 0] + s_redf[128 + L * 8 + 2]
                            + s_redf[128 + L * 8 + 4] + s_redf[128 + L * 8 + 6];
            const float ssq = s_redf[128 + L * 8 + 1] + s_redf[128 + L * 8 + 3]
                            + s_redf[128 + L * 8 + 5] + s_redf[128 + L * 8 + 7];
            const float mean = sum * (1.0f / 2048.0f);
            const float var = fmaxf(ssq * (1.0f / 2048.0f) - mean * mean, 0.0f);
            const float inv = rsqrtf(var + LN_EPS);
            #pragma unroll
            for (int nfi = 0; nfi < 2; ++nfi)
                #pragma unroll
                for (int r = 0; r < 4; ++r) {
                    const int srow = mfA * 16 + lg * 4 + r;
                    const int e = (nfb + nfi) * 16 + l15;
                    const int col = srow * 64 + e;
                    const float z = (q2[nfi][r] - mean) * inv * xg[L * 2048 + col] + xb[L * 2048 + col];
                    q2[nfi][r] = (L == 0) ? 2.0f * z : z;
                }
        }
    }

    // ---- emit bf16 hi/lo in fl1's blocked layout ----
    if (tid < 256) {
        #pragma unroll
        for (int nfi = 0; nfi < 2; ++nfi)
            #pragma unroll
            for (int r = 0; r < 4; ++r) {
                const int srow = mfA * 16 + lg * 4 + r;
                const int e = (nfb + nfi) * 16 + l15;
                const int col = srow * 64 + e;
                const float val = q2[nfi][r];
                const unsigned short hh = f2bf(val);
                const size_t addr = ((size_t)(m2 * 64 + (col >> 5)) * 256 + b2) * 32 + (col & 31);
                Ah[addr] = hh;
                Al[addr] = f2bf(val - bf2f(hh));
            }
    }
    #undef LOADQKV
    #undef LOADO
    #undef WRITEW
    #undef PROJ
}

// ---------------------------------------------------------------------------
// K4: fl1 MFMA GEMM, 3-term bf16 hi/lo split (unchanged)
// ---------------------------------------------------------------------------
__global__ __launch_bounds__(512) void k_fl1(
    const unsigned short* __restrict__ Ah,
    const unsigned short* __restrict__ Al,
    const float* __restrict__ W,
    float* __restrict__ part)
{
    __shared__ __align__(16) unsigned short s_wh[128 * 64];
    __shared__ __align__(16) unsigned short s_wl[128 * 64];

    const int nb  = blockIdx.x;
    const int kb  = blockIdx.y;
    const int tid = threadIdx.x;
    const int lane = tid & 63;
    const int wid  = tid >> 6;
    const int wm = wid >> 1;
    const int wn = wid & 1;

    const int sn = tid & 127;
    const int sq = tid >> 7;
    const int k0 = kb * 512;

    f32x4 acc[4][4];
    #pragma unroll
    for (int i = 0; i < 4; ++i)
        #pragma unroll
        for (int j = 0; j < 4; ++j)
            acc[i][j] = (f32x4){0.0f, 0.0f, 0.0f, 0.0f};

    float wreg[16];
    {
        const float* wp = W + (size_t)(k0 + sq * 16) * 512 + nb * 128 + sn;
        #pragma unroll
        for (int j = 0; j < 16; ++j) wreg[j] = wp[(size_t)j * 512];
    }

    const int hsn = sn & 7;
    const int wbase = sn * 64;
    const int wo0 = (((sq * 2) ^ hsn) << 3);
    const int wo1 = (((sq * 2 + 1) ^ hsn) << 3);

    for (int tt = 0; tt < 8; ++tt) {
        __syncthreads();
        {
            short8v h0, h1, l0, l1;
            #pragma unroll
            for (int j = 0; j < 8; ++j) {
                const unsigned short ha = f2bf(wreg[j]);
                const unsigned short hb = f2bf(wreg[j + 8]);
                h0[j] = (short)ha;
                h1[j] = (short)hb;
                l0[j] = (short)f2bf(wreg[j] - bf2f(ha));
                l1[j] = (short)f2bf(wreg[j + 8] - bf2f(hb));
            }
            *(short8v*)&s_wh[wbase + wo0] = h0;
            *(short8v*)&s_wh[wbase + wo1] = h1;
            *(short8v*)&s_wl[wbase + wo0] = l0;
            *(short8v*)&s_wl[wbase + wo1] = l1;
        }
        if (tt < 7) {
            const float* wp = W + (size_t)(k0 + (tt + 1) * 64 + sq * 16) * 512 + nb * 128 + sn;
            #pragma unroll
            for (int j = 0; j < 16; ++j) wreg[j] = wp[(size_t)j * 512];
        }
        __syncthreads();

        #pragma unroll
        for (int ks = 0; ks < 2; ++ks) {
            const int ktile = (k0 >> 5) + tt * 2 + ks;
            const size_t abase = ((size_t)ktile * 256 + wm * 64 + (lane & 15)) * 32
                               + (lane >> 4) * 8;
            short8v ahf[4], alf[4];
            #pragma unroll
            for (int mf = 0; mf < 4; ++mf) {
                ahf[mf] = *(const short8v*)&Ah[abase + (size_t)mf * 512];
                alf[mf] = *(const short8v*)&Al[abase + (size_t)mf * 512];
            }
            short8v bhf[4], blf[4];
            #pragma unroll
            for (int nf = 0; nf < 4; ++nf) {
                const int n = wn * 64 + nf * 16 + (lane & 15);
                const int q = ks * 4 + (lane >> 4);
                const int baddr = n * 64 + ((q ^ (n & 7)) << 3);
                bhf[nf] = *(const short8v*)&s_wh[baddr];
                blf[nf] = *(const short8v*)&s_wl[baddr];
            }
            #pragma unroll
            for (int mf = 0; mf < 4; ++mf)
                #pragma unroll
                for (int nf = 0; nf < 4; ++nf) {
                    MFMA3(acc[mf][nf], ahf[mf], alf[mf], bhf[nf], blf[nf]);
                }
        }
    }

    float* pp = part + (size_t)kb * 131072 + (size_t)nb * 128;
    const int r0 = (lane >> 4) * 4;
    const int c  = lane & 15;
    #pragma unroll
    for (int mf = 0; mf < 4; ++mf) {
        const int row = wm * 64 + mf * 16 + r0;
        #pragma unroll
        for (int nf = 0; nf < 4; ++nf) {
            const int col = wn * 64 + nf * 16 + c;
            #pragma unroll
            for (int r = 0; r < 4; ++r)
                pp[(size_t)(row + r) * 512 + col] = acc[mf][nf][r];
        }
    }
}

// ---------------------------------------------------------------------------
// K5: fused tail — fl1 reduce+bias+relu -> fl2 -> fl3 (unchanged)
// ---------------------------------------------------------------------------
__global__ __launch_bounds__(256) void k_tail(
    const float* __restrict__ part, const float* __restrict__ fb1,
    const float* __restrict__ w2,   const float* __restrict__ fb2,
    const float* __restrict__ w3,   const float* __restrict__ fb3,
    float* __restrict__ out)
{
    __shared__ float s_u1[512];
    __shared__ float s_u2[128];
    const int r = blockIdx.x, tid = threadIdx.x;

    if (tid < 128) {
        const int i4 = r * 512 + tid * 4;
        float4 s = *(const float4*)&fb1[tid * 4];
        for (int ks = 0; ks < 64; ++ks) {
            const float4 p = *(const float4*)&part[(size_t)ks * 131072 + i4];
            s.x += p.x; s.y += p.y; s.z += p.z; s.w += p.w;
        }
        s.x = fmaxf(s.x, 0.0f); s.y = fmaxf(s.y, 0.0f);
        s.z = fmaxf(s.z, 0.0f); s.w = fmaxf(s.w, 0.0f);
        *(float4*)&s_u1[tid * 4] = s;
    }
    __syncthreads();

    if (tid < 128) {
        float acc = fb2[tid];
        for (int k = 0; k < 512; k++) acc += s_u1[k] * w2[k * 128 + tid];
        s_u2[tid] = fmaxf(acc, 0.0f);
    }
    __syncthreads();

    if (tid < 25) {
        float acc = fb3[tid];
        for (int k = 0; k < 128; k++) acc += s_u2[k] * w3[k * 25 + tid];
        out[r * 25 + tid] = acc;
    }
}

// ---------------------------------------------------------------------------
extern "C" void kernel_launch(void* const* d_in, const int* in_sizes, int n_in,
                              void* d_out, int out_size, void* d_ws, size_t ws_size,
                              hipStream_t stream)
{
    const float* t      = (const float*)d_in[0];
    const float* c1w    = (const float*)d_in[1];
    const float* c1b    = (const float*)d_in[2];
    const float* c2w    = (const float*)d_in[3];
    const float* c2b    = (const float*)d_in[4];
    const float* ew     = (const float*)d_in[5];
    const float* eb     = (const float*)d_in[6];
    const float* mh_wq  = (const float*)d_in[7];
    const float* mh_bq  = (const float*)d_in[8];
    const float* mh_wk  = (const float*)d_in[9];
    const float* mh_bk  = (const float*)d_in[10];
    const float* mh_wv  = (const float*)d_in[11];
    const float* mh_bv  = (const float*)d_in[12];
    const float* mh_wo  = (const float*)d_in[13];
    const float* mh_bo  = (const float*)d_in[14];
    const float* ln1_g  = (const float*)d_in[15];
    const float* ln1_b  = (const float*)d_in[16];
    // d_in[17..24]: XL attention weights -- dead code in the reference, unused
    const float* xln_g  = (const float*)d_in[25];
    const float* xln_b  = (const float*)d_in[26];
    const float* fl1_w  = (const float*)d_in[27];
    const float* fl1_b  = (const float*)d_in[28];
    const float* fl2_w  = (const float*)d_in[29];
    const float* fl2_b  = (const float*)d_in[30];
    const float* fl3_w  = (const float*)d_in[31];
    const float* fl3_b  = (const float*)d_in[32];
    (void)in_sizes; (void)n_in; (void)out_size; (void)ws_size;

    float* U   = (float*)d_ws;                 // PART
    float* U2  = U + 8388608;                  // Ah/Al
    unsigned short* Ah = (unsigned short*)U2;
    unsigned short* Al = Ah + 8388608;
    float* PART = U;
    float* out  = (float*)d_out;

    k_fused<<<4096, 512, 0, stream>>>(t, c1w, c1b, c2w, c2b, ew, eb,
                                      mh_wq, mh_bq, mh_wk, mh_bk, mh_wv, mh_bv,
                                      mh_wo, mh_bo, ln1_g, ln1_b, xln_g, xln_b,
                                      Ah, Al);
    k_fl1<<<dim3(4, 64), 512, 0, stream>>>(Ah, Al, fl1_w, PART);
    k_tail<<<256, 256, 0, stream>>>(PART, fl1_b, fl2_w, fl2_b, fl3_w, fl3_b, out);
}

// Round 14
// 256.665 us; speedup vs baseline: 1.0794x; 1.0377x over previous
//
#include <hip/hip_runtime.h>
#include <hip/hip_bf16.h>
#include <math.h>

#define LN_EPS 1e-5f

typedef __attribute__((ext_vector_type(8))) short short8v;
typedef __attribute__((ext_vector_type(4))) float f32x4;

static __device__ __forceinline__ unsigned short f2bf(float x) {
    unsigned u = __float_as_uint(x);
    u += 0x7fffu + ((u >> 16) & 1u);
    return (unsigned short)(u >> 16);
}
static __device__ __forceinline__ float bf2f(unsigned short h) {
    return __uint_as_float(((unsigned)h) << 16);
}

#define MFMA3(ACC, AH, AL, BH, BL)                                          \
    ACC = __builtin_amdgcn_mfma_f32_16x16x32_bf16(AH, BH, ACC, 0, 0, 0);    \
    ACC = __builtin_amdgcn_mfma_f32_16x16x32_bf16(AL, BH, ACC, 0, 0, 0);    \
    ACC = __builtin_amdgcn_mfma_f32_16x16x32_bf16(AH, BL, ACC, 0, 0, 0);

// ---------------------------------------------------------------------------
// K1: FUSED per-patch pipeline: conv1+pool (f32) -> conv2 (MFMA) + shfl-pool
//     -> expansion -> 4-head attention (MFMA, ALL 8 waves) + LN(64)
//     + XL double-LN, emitting Ah/Al. Block = patch p (m = p>>8, b2 = p&255).
// r14: attn work split across 8 waves: wave w = (head h = w&3, row-half
// mfS = w>>2). Per-output MFMA chains unchanged; only LN partial-combine
// order differs (4 quarters / 8 wave partials).
// ---------------------------------------------------------------------------
__global__ __launch_bounds__(512, 4) void k_fused(
    const float* __restrict__ t,
    const float* __restrict__ c1w, const float* __restrict__ c1b,
    const float* __restrict__ c2w, const float* __restrict__ c2b,
    const float* __restrict__ ew,  const float* __restrict__ eb,
    const float* __restrict__ wq, const float* __restrict__ bq,
    const float* __restrict__ wk, const float* __restrict__ bk,
    const float* __restrict__ wv, const float* __restrict__ bv,
    const float* __restrict__ wo, const float* __restrict__ bo,
    const float* __restrict__ g1, const float* __restrict__ b1,
    const float* __restrict__ xg, const float* __restrict__ xb,
    unsigned short* __restrict__ Ah, unsigned short* __restrict__ Al)
{
    __shared__ __align__(16) unsigned short s_W2[2][9216];   // 36864 B
    __shared__ __align__(16) unsigned short s_p1[14400];     // 28800 B
    __shared__ __align__(16) float s_s2[1152];               // 4608 B (+reds alias)
    __shared__ __align__(16) float s_uf[32 * 68];            // 8704 B
    __shared__ float s_c2b[32];

    // conv-phase aliases
    float* s_x  = (float*)s_W2;
    unsigned short* s_wh  = s_W2[0];
    unsigned short* s_wl  = s_W2[1];
    unsigned short* s_p1h = s_p1;
    unsigned short* s_p1l = s_p1 + 7200;
    float* s_ew = (float*)s_p1;
    // attn-phase aliases
    unsigned short* aw_h = s_W2[0];
    unsigned short* aw_l = s_W2[0] + 4096;
    unsigned short* R1   = s_p1;
    unsigned short* R2   = s_W2[1];
    unsigned short* qA_h = R1;
    unsigned short* qA_l = R1 + 3072;
    unsigned short* kB_h = R1 + 6144;
    unsigned short* kB_l = R1 + 9216;
    unsigned short* p_h  = R1;
    unsigned short* p_l  = R1 + 5120;
    unsigned short* vT_h = R2;
    unsigned short* vT_l = R2 + 2560;
    unsigned short* oA_h = R2;
    unsigned short* oA_l = R2 + 2816;
    float* s_redf = s_s2;     // [0..255] LN64 quarters, [256..287] XL partials

    const int p   = blockIdx.x;
    const int tid = threadIdx.x;

    // =================== conv section (r10, unchanged) ===================
    const int b = p >> 4, tile = p & 15, tr = tile >> 2, tc = tile & 3;
    const float* tp = t + (size_t)b * 128 * 128 + (size_t)tr * 32 * 128 + tc * 32;
    for (int i = tid; i < 1024; i += 512) {
        const int r = i >> 5, c = i & 31;
        s_x[r * 33 + c] = tp[r * 128 + c] * (1.0f / 255.0f);
    }
    if (tid < 32) s_c2b[tid] = c2b[tid];
    __syncthreads();

    if ((tid & 255) < 225) {
        const int pos  = tid & 255;
        const int half = tid >> 8;
        const int pi = pos / 15, pj = pos % 15;
        float xw[16];
        #pragma unroll
        for (int r = 0; r < 4; ++r)
            #pragma unroll
            for (int c = 0; c < 4; ++c)
                xw[r * 4 + c] = s_x[(2 * pi + r) * 33 + (2 * pj + c)];
        #pragma unroll
        for (int og2 = 0; og2 < 2; ++og2) {
            const int og = half * 2 + og2;
            short8v hb, lb;
            #pragma unroll
            for (int o = 0; o < 8; ++o) {
                const int oc = og * 8 + o;
                float w[9];
                #pragma unroll
                for (int j = 0; j < 9; ++j) w[j] = c1w[oc * 9 + j];
                float mx = -3.0e38f;
                #pragma unroll
                for (int a = 0; a < 2; ++a)
                    #pragma unroll
                    for (int bb = 0; bb < 2; ++bb) {
                        float s = xw[(a + 0) * 4 + bb + 0] * w[0]
                                + xw[(a + 0) * 4 + bb + 1] * w[1]
                                + xw[(a + 0) * 4 + bb + 2] * w[2]
                                + xw[(a + 1) * 4 + bb + 0] * w[3]
                                + xw[(a + 1) * 4 + bb + 1] * w[4]
                                + xw[(a + 1) * 4 + bb + 2] * w[5]
                                + xw[(a + 2) * 4 + bb + 0] * w[6]
                                + xw[(a + 2) * 4 + bb + 1] * w[7]
                                + xw[(a + 2) * 4 + bb + 2] * w[8];
                        mx = fmaxf(mx, s);
                    }
                const float val = mx + c1b[oc];
                const unsigned short h = f2bf(val);
                hb[o] = (short)h;
                lb[o] = (short)f2bf(val - bf2f(h));
            }
            *(short8v*)&s_p1h[og * 1800 + pos * 8] = hb;
            *(short8v*)&s_p1l[og * 1800 + pos * 8] = lb;
        }
    }
    __syncthreads();

    {
        const int oc  = tid >> 4;
        const int sub = tid & 15;
        const int kg  = sub >> 2;
        const int off = (sub * 2) & 7;
        const float* wp = c2w + oc * 288 + sub * 18;
        float wf[18];
        #pragma unroll
        for (int j = 0; j < 9; ++j)
            *(float2*)&wf[j * 2] = *(const float2*)&wp[j * 2];
        #pragma unroll
        for (int ks = 0; ks < 9; ++ks) {
            const float v0 = wf[ks];
            const float v1 = wf[9 + ks];
            const unsigned short h0 = f2bf(v0), h1 = f2bf(v1);
            const unsigned short l0 = f2bf(v0 - bf2f(h0));
            const unsigned short l1 = f2bf(v1 - bf2f(h1));
            const int idx = ks * 1024 + kg * 256 + oc * 8 + off;
            *(unsigned*)&s_wh[idx] = (unsigned)h0 | ((unsigned)h1 << 16);
            *(unsigned*)&s_wl[idx] = (unsigned)l0 | ((unsigned)l1 << 16);
        }
    }
    __syncthreads();

    {
        const int lane = tid & 63;
        const int w8   = tid >> 6;
        const int jcol = lane & 15;
        const int lg   = lane >> 4;

        {
            const int nt = w8;
            const int n = nt * 16 + jcol;
            const int pq = n >> 2, w4 = n & 3;
            const int pi = pq / 6, pj = pq - pi * 6;
            const int rbase = 2 * pi + (w4 >> 1);
            const int cbase = 2 * pj + (w4 & 1);

            f32x4 acc0 = {0,0,0,0}, acc1 = {0,0,0,0};
            #pragma unroll
            for (int ks = 0; ks < 9; ++ks) {
                const int dr = ks / 3, dc = ks - dr * 3;
                const int ab = ks * 1024 + lg * 256 + jcol * 8;
                const short8v ah0 = *(const short8v*)&s_wh[ab];
                const short8v ah1 = *(const short8v*)&s_wh[ab + 128];
                const short8v al0 = *(const short8v*)&s_wl[ab];
                const short8v al1 = *(const short8v*)&s_wl[ab + 128];
                const int wpos = (rbase + dr) * 15 + (cbase + dc);
                const int boff = lg * 1800 + wpos * 8;
                const short8v bh = *(const short8v*)&s_p1h[boff];
                const short8v bl = *(const short8v*)&s_p1l[boff];
                acc0 = __builtin_amdgcn_mfma_f32_16x16x32_bf16(ah0, bh, acc0, 0, 0, 0);
                acc0 = __builtin_amdgcn_mfma_f32_16x16x32_bf16(al0, bh, acc0, 0, 0, 0);
                acc0 = __builtin_amdgcn_mfma_f32_16x16x32_bf16(ah0, bl, acc0, 0, 0, 0);
                acc1 = __builtin_amdgcn_mfma_f32_16x16x32_bf16(ah1, bh, acc1, 0, 0, 0);
                acc1 = __builtin_amdgcn_mfma_f32_16x16x32_bf16(al1, bh, acc1, 0, 0, 0);
                acc1 = __builtin_amdgcn_mfma_f32_16x16x32_bf16(ah1, bl, acc1, 0, 0, 0);
            }
            #pragma unroll
            for (int mt = 0; mt < 2; ++mt)
                #pragma unroll
                for (int r = 0; r < 4; ++r) {
                    float v = (mt == 0) ? acc0[r] : acc1[r];
                    v = fmaxf(v, __shfl_xor(v, 1));
                    v = fmaxf(v, __shfl_xor(v, 2));
                    if ((lane & 3) == 0) {
                        const int oc = mt * 16 + (lane >> 4) * 4 + r;
                        const int pq2 = nt * 4 + (jcol >> 2);
                        s_s2[oc * 36 + pq2] = v + s_c2b[oc];
                    }
                }
        }

        if (w8 < 2) {
            const int nt = 8;
            const int mt = w8;
            const int n = nt * 16 + jcol;
            const int pq = n >> 2, w4 = n & 3;
            const int pi = pq / 6, pj = pq - pi * 6;
            const int rbase = 2 * pi + (w4 >> 1);
            const int cbase = 2 * pj + (w4 & 1);

            f32x4 accX = {0,0,0,0};
            #pragma unroll
            for (int ks = 0; ks < 9; ++ks) {
                const int dr = ks / 3, dc = ks - dr * 3;
                const int ab = ks * 1024 + lg * 256 + jcol * 8 + mt * 128;
                const short8v ah = *(const short8v*)&s_wh[ab];
                const short8v al = *(const short8v*)&s_wl[ab];
                const int wpos = (rbase + dr) * 15 + (cbase + dc);
                const int boff = lg * 1800 + wpos * 8;
                const short8v bh = *(const short8v*)&s_p1h[boff];
                const short8v bl = *(const short8v*)&s_p1l[boff];
                accX = __builtin_amdgcn_mfma_f32_16x16x32_bf16(ah, bh, accX, 0, 0, 0);
                accX = __builtin_amdgcn_mfma_f32_16x16x32_bf16(al, bh, accX, 0, 0, 0);
                accX = __builtin_amdgcn_mfma_f32_16x16x32_bf16(ah, bl, accX, 0, 0, 0);
            }
            #pragma unroll
            for (int r = 0; r < 4; ++r) {
                float v = accX[r];
                v = fmaxf(v, __shfl_xor(v, 1));
                v = fmaxf(v, __shfl_xor(v, 2));
                if ((lane & 3) == 0) {
                    const int oc = mt * 16 + (lane >> 4) * 4 + r;
                    const int pq2 = nt * 4 + (jcol >> 2);
                    s_s2[oc * 36 + pq2] = v + s_c2b[oc];
                }
            }
        }
    }
    __syncthreads();

    // ---- stage ew + issue Wq loads ----
    const int m2 = p >> 8;
    const int b2 = p & 255;
    const int wn   = tid & 63;
    const int wkq8 = tid >> 6;
    float wreg[8];

    #define LOADQKV(SRC)                                                          \
        {                                                                         \
            const float* sp = (SRC) + (size_t)m2 * 4096 + (wn >> 4) * 1024 + (wn & 15); \
            _Pragma("unroll")                                                     \
            for (int j = 0; j < 8; ++j) wreg[j] = sp[(wkq8 * 8 + j) * 16];        \
        }
    #define LOADO(SRC)                                                            \
        {                                                                         \
            const float* sp = (SRC) + (size_t)m2 * 4096 + wn;                     \
            _Pragma("unroll")                                                     \
            for (int j = 0; j < 8; ++j) wreg[j] = sp[(wkq8 * 8 + j) * 64];        \
        }
    #define WRITEW()                                                              \
        {                                                                         \
            _Pragma("unroll")                                                     \
            for (int j2 = 0; j2 < 4; ++j2) {                                      \
                const int d = wkq8 * 8 + j2 * 2;                                  \
                const float v0 = wreg[j2 * 2], v1 = wreg[j2 * 2 + 1];             \
                const unsigned short h0 = f2bf(v0), h1 = f2bf(v1);                \
                const unsigned short q0 = f2bf(v0 - bf2f(h0));                    \
                const unsigned short q1 = f2bf(v1 - bf2f(h1));                    \
                const int idx = wn * 64 + (((d >> 3) ^ (wn & 7)) << 3) + (d & 7); \
                *(unsigned*)&aw_h[idx] = (unsigned)h0 | ((unsigned)h1 << 16);     \
                *(unsigned*)&aw_l[idx] = (unsigned)q0 | ((unsigned)q1 << 16);     \
            }                                                                     \
        }

    for (int i = tid; i < 576; i += 512)
        *(float4*)&s_ew[i * 4] = *(const float4*)&ew[i * 4];
    LOADQKV(wq);
    __syncthreads();

    // ---- phase C: expansion -> s_uf ----
    {
        const int s  = tid >> 4;
        const int e0 = (tid & 15) * 4;
        float acc4[4];
        *(float4*)&acc4[0] = *(const float4*)&eb[e0];
        for (int f = 0; f < 36; ++f) {
            const float sv = s_s2[s * 36 + f];
            const float4 w0 = *(const float4*)&s_ew[f * 64 + e0];
            acc4[0] += sv * w0.x; acc4[1] += sv * w0.y;
            acc4[2] += sv * w0.z; acc4[3] += sv * w0.w;
        }
        float4 o0;
        o0.x = fmaxf(acc4[0], 0.0f); o0.y = fmaxf(acc4[1], 0.0f);
        o0.z = fmaxf(acc4[2], 0.0f); o0.w = fmaxf(acc4[3], 0.0f);
        *(float4*)&s_uf[s * 68 + e0] = o0;
    }
    __syncthreads();

    // =================== attn section — ALL 8 waves ===================
    const int l   = tid & 63;
    const int w   = tid >> 6;
    const int l15 = l & 15;
    const int lg  = l >> 4;
    const int h   = w & 3;       // head
    const int mfS = w >> 2;      // row half (0: rows 0-15, 1: rows 16-31)

    WRITEW();                    // Wq -> aw (conv W dead)

    short8v uh[2], ul[2];
    #pragma unroll
    for (int ks = 0; ks < 2; ++ks) {
        const float* pb = &s_uf[(mfS * 16 + l15) * 68 + (ks * 4 + lg) * 8];
        float xv[8];
        *(float4*)&xv[0] = *(const float4*)pb;
        *(float4*)&xv[4] = *(const float4*)(pb + 4);
        short8v hh, ll;
        #pragma unroll
        for (int j = 0; j < 8; ++j) {
            const unsigned short hq = f2bf(xv[j]);
            hh[j] = (short)hq;
            ll[j] = (short)f2bf(xv[j] - bf2f(hq));
        }
        uh[ks] = hh; ul[ks] = ll;
    }
    __syncthreads();             // Wq in LDS

    #define PROJ(BIAS, MODE)                                                      \
        {                                                                         \
            short8v wbh[2], wbl[2];                                               \
            const int bn = h * 16 + l15;                                          \
            _Pragma("unroll")                                                     \
            for (int ks = 0; ks < 2; ++ks) {                                      \
                const int off = bn * 64 + (((ks * 4 + lg) ^ (bn & 7)) << 3);      \
                wbh[ks] = *(const short8v*)&aw_h[off];                            \
                wbl[ks] = *(const short8v*)&aw_l[off];                            \
            }                                                                     \
            const float bias_v = (BIAS)[m2 * 64 + bn];                            \
            f32x4 a0 = {0,0,0,0};                                                 \
            _Pragma("unroll")                                                     \
            for (int ks = 0; ks < 2; ++ks) {                                      \
                MFMA3(a0, uh[ks], ul[ks], wbh[ks], wbl[ks]);                      \
            }                                                                     \
            _Pragma("unroll")                                                     \
            for (int r = 0; r < 4; ++r) {                                         \
                const float val = a0[r] + bias_v;                                 \
                const unsigned short hh = f2bf(val);                              \
                const unsigned short lo = f2bf(val - bf2f(hh));                   \
                const int srow = mfS * 16 + lg * 4 + r;                           \
                if ((MODE) == 0) { const int ix = h * 768 + srow * 24 + l15;      \
                    qA_h[ix] = hh; qA_l[ix] = lo; }                               \
                else if ((MODE) == 1) { const int ix = h * 768 + srow * 24 + l15; \
                    kB_h[ix] = hh; kB_l[ix] = lo; }                               \
                else { const int ix = h * 640 + l15 * 40 + srow;                  \
                    vT_h[ix] = hh; vT_l[ix] = lo; }                               \
            }                                                                     \
        }

    PROJ(bq, 0);
    LOADQKV(wk);
    __syncthreads();
    WRITEW();
    __syncthreads();

    PROJ(bk, 1);
    LOADQKV(wv);
    __syncthreads();
    WRITEW();
    __syncthreads();

    PROJ(bv, 2);
    LOADO(wo);
    __syncthreads();
    WRITEW();                    // Wo -> aw
    __syncthreads();

    // ---- scores + in-register softmax (rows mfS half of head h) ----
    float pvreg[2][4];
    {
        const short8v zz = {0,0,0,0,0,0,0,0};
        short8v qh, ql, kh[2], kl[2];
        const bool kreal = (lg < 2);
        if (kreal) {
            const int ia = h * 768 + (mfS * 16 + l15) * 24 + lg * 8;
            qh = *(const short8v*)&qA_h[ia];
            ql = *(const short8v*)&qA_l[ia];
            #pragma unroll
            for (int nf = 0; nf < 2; ++nf) {
                const int ik = h * 768 + (nf * 16 + l15) * 24 + lg * 8;
                kh[nf] = *(const short8v*)&kB_h[ik];
                kl[nf] = *(const short8v*)&kB_l[ik];
            }
        } else { qh = zz; ql = zz; kh[0] = zz; kl[0] = zz; kh[1] = zz; kl[1] = zz; }
        f32x4 sc[2];
        #pragma unroll
        for (int nf = 0; nf < 2; ++nf) {
            sc[nf] = (f32x4){0,0,0,0};
            MFMA3(sc[nf], qh, ql, kh[nf], kl[nf]);
        }
        #pragma unroll
        for (int r = 0; r < 4; ++r) {
            const float v0 = sc[0][r] * 0.25f;
            const float v1 = sc[1][r] * 0.25f;
            float mx = fmaxf(v0, v1);
            mx = fmaxf(mx, __shfl_xor(mx, 1));
            mx = fmaxf(mx, __shfl_xor(mx, 2));
            mx = fmaxf(mx, __shfl_xor(mx, 4));
            mx = fmaxf(mx, __shfl_xor(mx, 8));
            const float e0 = expf(v0 - mx), e1 = expf(v1 - mx);
            float sm = e0 + e1;
            sm += __shfl_xor(sm, 1);
            sm += __shfl_xor(sm, 2);
            sm += __shfl_xor(sm, 4);
            sm += __shfl_xor(sm, 8);
            const float inv = 1.0f / sm;
            pvreg[0][r] = e0 * inv;
            pvreg[1][r] = e1 * inv;
        }
    }
    __syncthreads();             // qA/kB reads complete

    #pragma unroll
    for (int nf = 0; nf < 2; ++nf)
        #pragma unroll
        for (int r = 0; r < 4; ++r) {
            const int srow = mfS * 16 + lg * 4 + r;
            const int tt = nf * 16 + l15;
            const int ix = h * 1280 + srow * 40 + tt;
            const float val = pvreg[nf][r];
            const unsigned short hh = f2bf(val);
            p_h[ix] = hh;
            p_l[ix] = f2bf(val - bf2f(hh));
        }
    __syncthreads();

    // ---- PV ----
    f32x4 ov;
    {
        const int ixp = h * 1280 + (mfS * 16 + l15) * 40 + lg * 8;
        const short8v ph = *(const short8v*)&p_h[ixp];
        const short8v pl = *(const short8v*)&p_l[ixp];
        const int iv = h * 640 + l15 * 40 + lg * 8;
        const short8v vh_ = *(const short8v*)&vT_h[iv];
        const short8v vl_ = *(const short8v*)&vT_l[iv];
        ov = (f32x4){0,0,0,0};
        MFMA3(ov, ph, pl, vh_, vl_);
    }
    __syncthreads();             // vT reads complete

    #pragma unroll
    for (int r = 0; r < 4; ++r) {
        const int srow = mfS * 16 + lg * 4 + r;
        const int dd = h * 16 + l15;
        const int ix = srow * 88 + dd;
        const float val = ov[r];
        const unsigned short hh = f2bf(val);
        oA_h[ix] = hh;
        oA_l[ix] = f2bf(val - bf2f(hh));
    }
    __syncthreads();

    // ---- o-proj + bias + residual + LN(64): wave = (row-half mfS, col-quarter h) ----
    const int n = h * 16 + l15;     // output col
    float x[4];
    {
        short8v oh[2], ol[2];
        #pragma unroll
        for (int ks = 0; ks < 2; ++ks) {
            const int ix = (mfS * 16 + l15) * 88 + (ks * 4 + lg) * 8;
            oh[ks] = *(const short8v*)&oA_h[ix];
            ol[ks] = *(const short8v*)&oA_l[ix];
        }
        f32x4 xe = {0,0,0,0};
        #pragma unroll
        for (int ks = 0; ks < 2; ++ks) {
            const int off = n * 64 + (((ks * 4 + lg) ^ (n & 7)) << 3);
            const short8v wbh = *(const short8v*)&aw_h[off];
            const short8v wbl = *(const short8v*)&aw_l[off];
            MFMA3(xe, oh[ks], ol[ks], wbh, wbl);
        }
        const float bo_v = bo[m2 * 64 + n];
        #pragma unroll
        for (int r = 0; r < 4; ++r) {
            const int srow = mfS * 16 + lg * 4 + r;
            x[r] = xe[r] + bo_v + s_uf[srow * 68 + n];
        }
    }
    #pragma unroll
    for (int r = 0; r < 4; ++r) {
        float s1 = x[r];
        float s2 = x[r] * x[r];
        s1 += __shfl_xor(s1, 1); s2 += __shfl_xor(s2, 1);
        s1 += __shfl_xor(s1, 2); s2 += __shfl_xor(s2, 2);
        s1 += __shfl_xor(s1, 4); s2 += __shfl_xor(s2, 4);
        s1 += __shfl_xor(s1, 8); s2 += __shfl_xor(s2, 8);
        if (l15 == 0) {
            const int srow = mfS * 16 + lg * 4 + r;
            s_redf[h * 64 + srow * 2 + 0] = s1;
            s_redf[h * 64 + srow * 2 + 1] = s2;
        }
    }
    __syncthreads();

    float q2[4];
    #pragma unroll
    for (int r = 0; r < 4; ++r) {
        const int srow = mfS * 16 + lg * 4 + r;
        const float sum = s_redf[srow * 2 + 0] + s_redf[64 + srow * 2 + 0]
                        + s_redf[128 + srow * 2 + 0] + s_redf[192 + srow * 2 + 0];
        const float ssq = s_redf[srow * 2 + 1] + s_redf[64 + srow * 2 + 1]
                        + s_redf[128 + srow * 2 + 1] + s_redf[192 + srow * 2 + 1];
        const float mean = sum * (1.0f / 64.0f);
        const float var = fmaxf(ssq * (1.0f / 64.0f) - mean * mean, 0.0f);
        const float inv = rsqrtf(var + LN_EPS);
        const float y = (x[r] - mean) * inv * g1[n] + b1[n];
        q2[r] = 2.0f * y;
    }

    // ---- fused XL double-LN over the 2048 row ----
    #pragma unroll
    for (int L = 0; L < 2; ++L) {
        float ls = 0.0f, lq = 0.0f;
        #pragma unroll
        for (int r = 0; r < 4; ++r) { ls += q2[r]; lq += q2[r] * q2[r]; }
        ls += __shfl_xor(ls, 1);  lq += __shfl_xor(lq, 1);
        ls += __shfl_xor(ls, 2);  lq += __shfl_xor(lq, 2);
        ls += __shfl_xor(ls, 4);  lq += __shfl_xor(lq, 4);
        ls += __shfl_xor(ls, 8);  lq += __shfl_xor(lq, 8);
        ls += __shfl_xor(ls, 16); lq += __shfl_xor(lq, 16);
        ls += __shfl_xor(ls, 32); lq += __shfl_xor(lq, 32);
        if (l == 0) {
            s_redf[256 + L * 16 + w * 2 + 0] = ls;
            s_redf[256 + L * 16 + w * 2 + 1] = lq;
        }
        __syncthreads();
        float sum = 0.0f, ssq = 0.0f;
        #pragma unroll
        for (int ww = 0; ww < 8; ++ww) {
            sum += s_redf[256 + L * 16 + ww * 2 + 0];
            ssq += s_redf[256 + L * 16 + ww * 2 + 1];
        }
        const float mean = sum * (1.0f / 2048.0f);
        const float var = fmaxf(ssq * (1.0f / 2048.0f) - mean * mean, 0.0f);
        const float inv = rsqrtf(var + LN_EPS);
        #pragma unroll
        for (int r = 0; r < 4; ++r) {
            const int srow = mfS * 16 + lg * 4 + r;
            const int col = srow * 64 + n;
            const float z = (q2[r] - mean) * inv * xg[L * 2048 + col] + xb[L * 2048 + col];
            q2[r] = (L == 0) ? 2.0f * z : z;
        }
    }

    // ---- emit bf16 hi/lo in fl1's blocked layout ----
    #pragma unroll
    for (int r = 0; r < 4; ++r) {
        const int srow = mfS * 16 + lg * 4 + r;
        const int col = srow * 64 + n;
        const float val = q2[r];
        const unsigned short hh = f2bf(val);
        const size_t addr = ((size_t)(m2 * 64 + (col >> 5)) * 256 + b2) * 32 + (col & 31);
        Ah[addr] = hh;
        Al[addr] = f2bf(val - bf2f(hh));
    }
    #undef LOADQKV
    #undef LOADO
    #undef WRITEW
    #undef PROJ
}

// ---------------------------------------------------------------------------
// K4: fl1 MFMA GEMM, 3-term bf16 hi/lo split (unchanged)
// ---------------------------------------------------------------------------
__global__ __launch_bounds__(512) void k_fl1(
    const unsigned short* __restrict__ Ah,
    const unsigned short* __restrict__ Al,
    const float* __restrict__ W,
    float* __restrict__ part)
{
    __shared__ __align__(16) unsigned short s_wh[128 * 64];
    __shared__ __align__(16) unsigned short s_wl[128 * 64];

    const int nb  = blockIdx.x;
    const int kb  = blockIdx.y;
    const int tid = threadIdx.x;
    const int lane = tid & 63;
    const int wid  = tid >> 6;
    const int wm = wid >> 1;
    const int wn = wid & 1;

    const int sn = tid & 127;
    const int sq = tid >> 7;
    const int k0 = kb * 512;

    f32x4 acc[4][4];
    #pragma unroll
    for (int i = 0; i < 4; ++i)
        #pragma unroll
        for (int j = 0; j < 4; ++j)
            acc[i][j] = (f32x4){0.0f, 0.0f, 0.0f, 0.0f};

    float wreg[16];
    {
        const float* wp = W + (size_t)(k0 + sq * 16) * 512 + nb * 128 + sn;
        #pragma unroll
        for (int j = 0; j < 16; ++j) wreg[j] = wp[(size_t)j * 512];
    }

    const int hsn = sn & 7;
    const int wbase = sn * 64;
    const int wo0 = (((sq * 2) ^ hsn) << 3);
    const int wo1 = (((sq * 2 + 1) ^ hsn) << 3);

    for (int tt = 0; tt < 8; ++tt) {
        __syncthreads();
        {
            short8v h0, h1, l0, l1;
            #pragma unroll
            for (int j = 0; j < 8; ++j) {
                const unsigned short ha = f2bf(wreg[j]);
                const unsigned short hb = f2bf(wreg[j + 8]);
                h0[j] = (short)ha;
                h1[j] = (short)hb;
                l0[j] = (short)f2bf(wreg[j] - bf2f(ha));
                l1[j] = (short)f2bf(wreg[j + 8] - bf2f(hb));
            }
            *(short8v*)&s_wh[wbase + wo0] = h0;
            *(short8v*)&s_wh[wbase + wo1] = h1;
            *(short8v*)&s_wl[wbase + wo0] = l0;
            *(short8v*)&s_wl[wbase + wo1] = l1;
        }
        if (tt < 7) {
            const float* wp = W + (size_t)(k0 + (tt + 1) * 64 + sq * 16) * 512 + nb * 128 + sn;
            #pragma unroll
            for (int j = 0; j < 16; ++j) wreg[j] = wp[(size_t)j * 512];
        }
        __syncthreads();

        #pragma unroll
        for (int ks = 0; ks < 2; ++ks) {
            const int ktile = (k0 >> 5) + tt * 2 + ks;
            const size_t abase = ((size_t)ktile * 256 + wm * 64 + (lane & 15)) * 32
                               + (lane >> 4) * 8;
            short8v ahf[4], alf[4];
            #pragma unroll
            for (int mf = 0; mf < 4; ++mf) {
                ahf[mf] = *(const short8v*)&Ah[abase + (size_t)mf * 512];
                alf[mf] = *(const short8v*)&Al[abase + (size_t)mf * 512];
            }
            short8v bhf[4], blf[4];
            #pragma unroll
            for (int nf = 0; nf < 4; ++nf) {
                const int n = wn * 64 + nf * 16 + (lane & 15);
                const int q = ks * 4 + (lane >> 4);
                const int baddr = n * 64 + ((q ^ (n & 7)) << 3);
                bhf[nf] = *(const short8v*)&s_wh[baddr];
                blf[nf] = *(const short8v*)&s_wl[baddr];
            }
            #pragma unroll
            for (int mf = 0; mf < 4; ++mf)
                #pragma unroll
                for (int nf = 0; nf < 4; ++nf) {
                    MFMA3(acc[mf][nf], ahf[mf], alf[mf], bhf[nf], blf[nf]);
                }
        }
    }

    float* pp = part + (size_t)kb * 131072 + (size_t)nb * 128;
    const int r0 = (lane >> 4) * 4;
    const int c  = lane & 15;
    #pragma unroll
    for (int mf = 0; mf < 4; ++mf) {
        const int row = wm * 64 + mf * 16 + r0;
        #pragma unroll
        for (int nf = 0; nf < 4; ++nf) {
            const int col = wn * 64 + nf * 16 + c;
            #pragma unroll
            for (int r = 0; r < 4; ++r)
                pp[(size_t)(row + r) * 512 + col] = acc[mf][nf][r];
        }
    }
}

// ---------------------------------------------------------------------------
// K5: fused tail — fl1 reduce+bias+relu -> fl2 -> fl3 (unchanged)
// ---------------------------------------------------------------------------
__global__ __launch_bounds__(256) void k_tail(
    const float* __restrict__ part, const float* __restrict__ fb1,
    const float* __restrict__ w2,   const float* __restrict__ fb2,
    const float* __restrict__ w3,   const float* __restrict__ fb3,
    float* __restrict__ out)
{
    __shared__ float s_u1[512];
    __shared__ float s_u2[128];
    const int r = blockIdx.x, tid = threadIdx.x;

    if (tid < 128) {
        const int i4 = r * 512 + tid * 4;
        float4 s = *(const float4*)&fb1[tid * 4];
        for (int ks = 0; ks < 64; ++ks) {
            const float4 p = *(const float4*)&part[(size_t)ks * 131072 + i4];
            s.x += p.x; s.y += p.y; s.z += p.z; s.w += p.w;
        }
        s.x = fmaxf(s.x, 0.0f); s.y = fmaxf(s.y, 0.0f);
        s.z = fmaxf(s.z, 0.0f); s.w = fmaxf(s.w, 0.0f);
        *(float4*)&s_u1[tid * 4] = s;
    }
    __syncthreads();

    if (tid < 128) {
        float acc = fb2[tid];
        for (int k = 0; k < 512; k++) acc += s_u1[k] * w2[k * 128 + tid];
        s_u2[tid] = fmaxf(acc, 0.0f);
    }
    __syncthreads();

    if (tid < 25) {
        float acc = fb3[tid];
        for (int k = 0; k < 128; k++) acc += s_u2[k] * w3[k * 25 + tid];
        out[r * 25 + tid] = acc;
    }
}

// ---------------------------------------------------------------------------
extern "C" void kernel_launch(void* const* d_in, const int* in_sizes, int n_in,
                              void* d_out, int out_size, void* d_ws, size_t ws_size,
                              hipStream_t stream)
{
    const float* t      = (const float*)d_in[0];
    const float* c1w    = (const float*)d_in[1];
    const float* c1b    = (const float*)d_in[2];
    const float* c2w    = (const float*)d_in[3];
    const float* c2b    = (const float*)d_in[4];
    const float* ew     = (const float*)d_in[5];
    const float* eb     = (const float*)d_in[6];
    const float* mh_wq  = (const float*)d_in[7];
    const float* mh_bq  = (const float*)d_in[8];
    const float* mh_wk  = (const float*)d_in[9];
    const float* mh_bk  = (const float*)d_in[10];
    const float* mh_wv  = (const float*)d_in[11];
    const float* mh_bv  = (const float*)d_in[12];
    const float* mh_wo  = (const float*)d_in[13];
    const float* mh_bo  = (const float*)d_in[14];
    const float* ln1_g  = (const float*)d_in[15];
    const float* ln1_b  = (const float*)d_in[16];
    // d_in[17..24]: XL attention weights -- dead code in the reference, unused
    const float* xln_g  = (const float*)d_in[25];
    const float* xln_b  = (const float*)d_in[26];
    const float* fl1_w  = (const float*)d_in[27];
    const float* fl1_b  = (const float*)d_in[28];
    const float* fl2_w  = (const float*)d_in[29];
    const float* fl2_b  = (const float*)d_in[30];
    const float* fl3_w  = (const float*)d_in[31];
    const float* fl3_b  = (const float*)d_in[32];
    (void)in_sizes; (void)n_in; (void)out_size; (void)ws_size;

    float* U   = (float*)d_ws;                 // PART
    float* U2  = U + 8388608;                  // Ah/Al
    unsigned short* Ah = (unsigned short*)U2;
    unsigned short* Al = Ah + 8388608;
    float* PART = U;
    float* out  = (float*)d_out;

    k_fused<<<4096, 512, 0, stream>>>(t, c1w, c1b, c2w, c2b, ew, eb,
                                      mh_wq, mh_bq, mh_wk, mh_bk, mh_wv, mh_bv,
                                      mh_wo, mh_bo, ln1_g, ln1_b, xln_g, xln_b,
                                      Ah, Al);
    k_fl1<<<dim3(4, 64), 512, 0, stream>>>(Ah, Al, fl1_w, PART);
    k_tail<<<256, 256, 0, stream>>>(PART, fl1_b, fl2_w, fl2_b, fl3_w, fl3_b, out);
}